// Round 12
// baseline (326.868 us; speedup 1.0000x reference)
//
#include <hip/hip_runtime.h>
#include <hip/hip_bf16.h>

// ============================================================================
// IDASR pipeline on gfx950 — round 12.
// Changes vs round 11:
//  * coord_mlp: one kernel fuses c1 GEMM + relu + c2 GEMM + softmax (was 3
//    latency-bound dispatches, one of them 64-block).
//  * pack_all: single weight-pack launch (was 2).
//  * gemm_qkv: QSPLIT 2->3 (1152 blocks, 4.5/CU).
// ============================================================================

typedef unsigned short u16;
typedef unsigned int u32;
using frag_ab = __attribute__((ext_vector_type(8))) short;  // 8 x bf16
using frag_cd = __attribute__((ext_vector_type(4))) float;  // 4 x f32 acc

#define HW 4096
#define NQ 4096
#define KBIG 12576
#define SPLITK 16
#define KCHUNK 800
#define KQ 2304
#define QSPLIT 3
#define QCHUNK 768

static __device__ __forceinline__ u16 f2b(float f) {
  union { __hip_bfloat16 h; u16 u; } c; c.h = __float2bfloat16(f); return c.u;
}
static __device__ __forceinline__ float b2f(u16 v) {
  return __uint_as_float((u32)v << 16);
}
static __device__ __forceinline__ u32 pk2(float a, float b) {
  union { __hip_bfloat162 h; u32 u; } c;
  c.h = __float22bfloat162_rn(float2{a, b});
  return c.u;
}
// async global->LDS, 16B per lane. LDS dest is wave-uniform base + lane*16.
static __device__ __forceinline__ void glds16(const u16* g, u16* l) {
  __builtin_amdgcn_global_load_lds(
      (const __attribute__((address_space(1))) u32*)(g),
      (__attribute__((address_space(3))) u32*)(l), 16, 0, 0);
}

#define BM 64
#define BN 64
#define BK 32
#define LDSS 40   // padded lds row stride for reg-staged tiles

// ---------------------------------------------------------------------------
// Generic bf16 GEMM (64x64 tile): used for the off2 layer.
// ---------------------------------------------------------------------------
__global__ __launch_bounds__(256)
void gemm_bt(const u16* __restrict__ A, const u16* __restrict__ Bt,
             void* __restrict__ Cv, const float* __restrict__ bias,
             int N, int K, int ldc, int flags,   // 1=relu, 2=bf16 out
             long sA, long sB, long sC, int sBias)
{
  __shared__ u16 As[BM * LDSS];
  __shared__ u16 Bs[BN * LDSS];
  const int z = blockIdx.z;
  A  += (long)z * sA;
  Bt += (long)z * sB;
  const float* bz = bias ? bias + (long)z * sBias : nullptr;

  const int tid  = threadIdx.x;
  const int m0   = blockIdx.x * BM;
  const int n0   = blockIdx.y * BN;
  const int wave = tid >> 6, lane = tid & 63;
  const int mw = (wave & 1) * 32, nw = (wave >> 1) * 32;
  const int lr = lane & 15, lk = lane >> 4;
  const int srow = tid >> 2, scol = (tid & 3) * 8;

  frag_cd acc[2][2] = {};
  const u16* aptr = A + (size_t)(m0 + srow) * K + scol;
  const bool bok  = (n0 + srow) < N;
  const u16* bptr = Bt + (size_t)(n0 + srow) * K + scol;

  uint4 av = *(const uint4*)(aptr);
  uint4 bv = bok ? *(const uint4*)(bptr) : uint4{0u, 0u, 0u, 0u};

  for (int k0 = 0; k0 < K; k0 += BK) {
    *(uint4*)&As[srow * LDSS + scol] = av;
    *(uint4*)&Bs[srow * LDSS + scol] = bv;
    __syncthreads();
    if (k0 + BK < K) {
      av = *(const uint4*)(aptr + k0 + BK);
      bv = bok ? *(const uint4*)(bptr + k0 + BK) : uint4{0u, 0u, 0u, 0u};
    }
    frag_ab af0 = *(const frag_ab*)&As[(mw      + lr) * LDSS + lk * 8];
    frag_ab af1 = *(const frag_ab*)&As[(mw + 16 + lr) * LDSS + lk * 8];
    frag_ab bf0 = *(const frag_ab*)&Bs[(nw      + lr) * LDSS + lk * 8];
    frag_ab bf1 = *(const frag_ab*)&Bs[(nw + 16 + lr) * LDSS + lk * 8];
    acc[0][0] = __builtin_amdgcn_mfma_f32_16x16x32_bf16(af0, bf0, acc[0][0], 0, 0, 0);
    acc[0][1] = __builtin_amdgcn_mfma_f32_16x16x32_bf16(af0, bf1, acc[0][1], 0, 0, 0);
    acc[1][0] = __builtin_amdgcn_mfma_f32_16x16x32_bf16(af1, bf0, acc[1][0], 0, 0, 0);
    acc[1][1] = __builtin_amdgcn_mfma_f32_16x16x32_bf16(af1, bf1, acc[1][1], 0, 0, 0);
    __syncthreads();
  }

  const bool relu = flags & 1;
  const bool obf  = flags & 2;
  #pragma unroll
  for (int i = 0; i < 2; i++)
    #pragma unroll
    for (int j = 0; j < 2; j++) {
      int col = n0 + nw + j * 16 + lr;
      if (col >= N) continue;
      float badd = bz ? bz[col] : 0.f;
      #pragma unroll
      for (int r = 0; r < 4; r++) {
        int row = m0 + mw + i * 16 + lk * 4 + r;
        float v = acc[i][j][r] + badd;
        if (relu) v = fmaxf(v, 0.f);
        size_t idx = (size_t)z * sC + (size_t)row * ldc + col;
        if (obf) ((u16*)Cv)[idx] = f2b(v);
        else     ((float*)Cv)[idx] = v;
      }
    }
}

// ---------------------------------------------------------------------------
// Implicit-im2col conv GEMM, 64x64 tile (ch conv, grouped off1 conv).
// ---------------------------------------------------------------------------
template<int W3, int SH, int PAD>
__global__ __launch_bounds__(256)
void gemm_conv(const u16* __restrict__ feat, const u16* __restrict__ Bt,
               void* __restrict__ Cv, const float* __restrict__ bias,
               int N, int K, int ldc, int flags, int FC, int cbStride,
               long sB, long sC, int sBias)
{
  __shared__ u16 As[BM * LDSS];
  __shared__ u16 Bs[BN * LDSS];
  const int z = blockIdx.z;
  Bt += (long)z * sB;
  const float* bz = bias ? bias + (long)z * sBias : nullptr;
  const int cb = z * cbStride;

  const int tid  = threadIdx.x;
  const int m0   = blockIdx.x * BM;
  const int n0   = blockIdx.y * BN;
  const int wave = tid >> 6, lane = tid & 63;
  const int mw = (wave & 1) * 32, nw = (wave >> 1) * 32;
  const int lr = lane & 15, lk = lane >> 4;
  const int srow = tid >> 2, scol = (tid & 3) * 8;
  const int p = m0 + srow, y = p >> 6, x = p & 63;

  frag_cd acc[2][2] = {};
  const bool bok  = (n0 + srow) < N;
  const u16* bptr = Bt + (size_t)(n0 + srow) * K + scol;

  auto stageA = [&](int k0) -> uint4 {
    int k = k0 + scol;
    int s = k >> SH;
    int c = k & ((1 << SH) - 1);
    int dy = s / W3, dx = s - dy * W3;
    int yy = y + dy - PAD, xx = x + dx - PAD;
    if (((unsigned)yy < 64u) && ((unsigned)xx < 64u))
      return *(const uint4*)&feat[(size_t)(yy * 64 + xx) * FC + cb + c];
    return uint4{0u, 0u, 0u, 0u};
  };

  uint4 av = stageA(0);
  uint4 bv = bok ? *(const uint4*)(bptr) : uint4{0u, 0u, 0u, 0u};

  for (int k0 = 0; k0 < K; k0 += BK) {
    *(uint4*)&As[srow * LDSS + scol] = av;
    *(uint4*)&Bs[srow * LDSS + scol] = bv;
    __syncthreads();
    if (k0 + BK < K) {
      av = stageA(k0 + BK);
      bv = bok ? *(const uint4*)(bptr + k0 + BK) : uint4{0u, 0u, 0u, 0u};
    }
    frag_ab af0 = *(const frag_ab*)&As[(mw      + lr) * LDSS + lk * 8];
    frag_ab af1 = *(const frag_ab*)&As[(mw + 16 + lr) * LDSS + lk * 8];
    frag_ab bf0 = *(const frag_ab*)&Bs[(nw      + lr) * LDSS + lk * 8];
    frag_ab bf1 = *(const frag_ab*)&Bs[(nw + 16 + lr) * LDSS + lk * 8];
    acc[0][0] = __builtin_amdgcn_mfma_f32_16x16x32_bf16(af0, bf0, acc[0][0], 0, 0, 0);
    acc[0][1] = __builtin_amdgcn_mfma_f32_16x16x32_bf16(af0, bf1, acc[0][1], 0, 0, 0);
    acc[1][0] = __builtin_amdgcn_mfma_f32_16x16x32_bf16(af1, bf0, acc[1][0], 0, 0, 0);
    acc[1][1] = __builtin_amdgcn_mfma_f32_16x16x32_bf16(af1, bf1, acc[1][1], 0, 0, 0);
    __syncthreads();
  }

  const bool relu = flags & 1;
  const bool obf  = flags & 2;
  #pragma unroll
  for (int i = 0; i < 2; i++)
    #pragma unroll
    for (int j = 0; j < 2; j++) {
      int col = n0 + nw + j * 16 + lr;
      if (col >= N) continue;
      float badd = bz ? bz[col] : 0.f;
      #pragma unroll
      for (int r = 0; r < 4; r++) {
        int row = m0 + mw + i * 16 + lk * 4 + r;
        float v = acc[i][j][r] + badd;
        if (relu) v = fmaxf(v, 0.f);
        size_t idx = (size_t)z * sC + (size_t)row * ldc + col;
        if (obf) ((u16*)Cv)[idx] = f2b(v);
        else     ((float*)Cv)[idx] = v;
      }
    }
}

// ---------------------------------------------------------------------------
// qkv conv GEMM: implicit im2col A, glds-B, split-K(3), bf16 partials.
// Tile 64x128, grid (64, 6, 3). Partials -> Pqb[z][row][col] (bf16).
// ---------------------------------------------------------------------------
__global__ __launch_bounds__(256)
void gemm_qkv(const u16* __restrict__ feat, const u16* __restrict__ Bt,
              u16* __restrict__ P)
{
  __shared__ u16 As[64 * LDSS];   // padded, reg-staged
  __shared__ u16 Bs[128 * 32];    // unpadded, glds target
  const int tid  = threadIdx.x;
  const int m0   = blockIdx.x * 64;
  const int n0   = blockIdx.y * 128;
  const int z    = blockIdx.z;
  const int kbeg = z * QCHUNK;
  const int kend = kbeg + QCHUNK;
  const int wave = tid >> 6, lane = tid & 63;
  const int nw = wave * 32;
  const int lr = lane & 15, lk = lane >> 4;
  const int arow = tid >> 2, acol = (tid & 3) * 8;
  const int p = m0 + arow, y = p >> 6, x = p & 63;

  frag_cd acc[4][2] = {};
  const u16* bbase = Bt + (size_t)(n0 + (tid >> 2)) * KQ + (tid & 3) * 8 + kbeg;
  u16* bdst = &Bs[(size_t)tid * 8];

  auto stageA = [&](int k0) -> uint4 {
    int k = k0 + acol;
    int s = k >> 8, c = k & 255;
    int dy = s / 3, dx = s - dy * 3;
    int yy = y + dy - 1, xx = x + dx - 1;
    if (((unsigned)yy < 64u) && ((unsigned)xx < 64u))
      return *(const uint4*)&feat[(size_t)(yy * 64 + xx) * 256 + c];
    return uint4{0u, 0u, 0u, 0u};
  };

  uint4 av = stageA(kbeg);

  for (int k0 = kbeg; k0 < kend; k0 += BK) {
    glds16(bbase + (k0 - kbeg), bdst);
    glds16(bbase + (k0 - kbeg) + (size_t)64 * KQ, bdst + 2048);
    *(uint4*)&As[arow * LDSS + acol] = av;
    __syncthreads();
    if (k0 + BK < kend) av = stageA(k0 + BK);
    frag_ab af[4];
    #pragma unroll
    for (int i = 0; i < 4; i++)
      af[i] = *(const frag_ab*)&As[(i * 16 + lr) * LDSS + lk * 8];
    #pragma unroll
    for (int j = 0; j < 2; j++) {
      frag_ab bf = *(const frag_ab*)&Bs[(nw + j * 16 + lr) * 32 + lk * 8];
      #pragma unroll
      for (int i = 0; i < 4; i++)
        acc[i][j] = __builtin_amdgcn_mfma_f32_16x16x32_bf16(af[i], bf, acc[i][j], 0, 0, 0);
    }
    __syncthreads();
  }

  #pragma unroll
  for (int i = 0; i < 4; i++)
    #pragma unroll
    for (int j = 0; j < 2; j++) {
      int col = n0 + nw + j * 16 + lr;
      #pragma unroll
      for (int r = 0; r < 4; r++) {
        int row = m0 + i * 16 + lk * 4 + r;
        P[(size_t)z * (NQ * 768) + (size_t)row * 768 + col] = f2b(acc[i][j][r]);
      }
    }
}

// sum QSPLIT bf16 qkv partials + bias -> fqkvb (bf16, all 768) and fqkvV
// (f32, V-section c>=512, compact 256/row). 8 elems/thread.
__global__ __launch_bounds__(256)
void reduce_qkv(const u16* __restrict__ P, const float* __restrict__ bias,
                u16* __restrict__ outb, float* __restrict__ outV)
{
  int i8 = blockIdx.x * 256 + threadIdx.x;
  if (i8 >= NQ * 96) return;
  size_t i = (size_t)i8 * 8;
  int row = (int)(i / 768);
  int c = (int)(i % 768);
  float v[8];
  #pragma unroll
  for (int t = 0; t < 8; t++) v[t] = bias[c + t];
  for (int z = 0; z < QSPLIT; z++) {
    uint4 a = *(const uint4*)&P[(size_t)z * (NQ * 768) + i];
    u32 aw[4] = {a.x, a.y, a.z, a.w};
    #pragma unroll
    for (int t = 0; t < 4; t++) {
      v[2 * t]     += __uint_as_float(aw[t] << 16);
      v[2 * t + 1] += __uint_as_float(aw[t] & 0xffff0000u);
    }
  }
  uint4 ob = {pk2(v[0], v[1]), pk2(v[2], v[3]), pk2(v[4], v[5]), pk2(v[6], v[7])};
  *(uint4*)&outb[i] = ob;
  if (c >= 512) {
    float* dst = outV + (size_t)row * 256 + (c - 512);
    *(float4*)dst       = float4{v[0], v[1], v[2], v[3]};
    *(float4*)(dst + 4) = float4{v[4], v[5], v[6], v[7]};
  }
}

// ---------------------------------------------------------------------------
// Big MLP GEMM: fused gather-A (f32 V, deferred pack), 128x256 tile, glds-B,
// split-K(16), bf16 partials. block 512 (8 waves), grid (32, 16) = 2/CU.
// ---------------------------------------------------------------------------
__global__ __launch_bounds__(512, 4)
void gemm_big(const u16* __restrict__ Bt, const float* __restrict__ fqkvV,
              const float* __restrict__ attnval, const int* __restrict__ vidx,
              const float* __restrict__ cell, u16* __restrict__ P)
{
  __shared__ u16 As[128 * LDSS];         // 10 KB padded, reg-staged gather
  __shared__ u16 Bs[256 * 32];           // 16 KB unpadded, glds target
  __shared__ int   s_vidx[5 * 128];      // 2.5 KB
  __shared__ float s_attn[5 * 128 * 8];  // 20 KB
  const int tid  = threadIdx.x;
  const int m0   = blockIdx.x * 128;
  const int z    = blockIdx.y;
  const int kbeg = z * KCHUNK;
  const int kend = min(KBIG, kbeg + KCHUNK);
  const int jbeg = kbeg >> 8;
  const int jcnt = ((kend - 1) >> 8) - jbeg + 1;   // <= 5
  const int wave = tid >> 6, lane = tid & 63;
  const int mw = (wave & 1) * 64, nwv = (wave >> 1) * 64;
  const int lr = lane & 15, lk = lane >> 4;
  const int arow = tid >> 2, acol = (tid & 3) * 8;  // 128 rows x 4x8
  const int q = m0 + arow;

  for (int t = tid; t < 128 * jcnt; t += 512) {
    int r = t & 127, jj = t >> 7;
    int j = jbeg + jj;
    s_vidx[t] = (j < 49) ? vidx[(m0 + r) * 49 + j] : -1;
  }
  for (int t = tid; t < 128 * 8 * jcnt; t += 512) {
    int h = t & 7, rr = (t >> 3) & 127, jj = t >> 10;
    int j = jbeg + jj;
    s_attn[t] = (j < 49) ? attnval[((size_t)((m0 + rr) * 49 + j)) * 8 + h] : 0.f;
  }
  __syncthreads();

  auto loadA = [&](int k0, float4& f0, float4& f1, float& w) {
    const int k = k0 + acol;
    const int j = k >> 8, c = k & 255;
    f0 = float4{0.f, 0.f, 0.f, 0.f};
    f1 = float4{0.f, 0.f, 0.f, 0.f};
    w = 0.f;
    if (j < 49) {
      const int jj = j - jbeg;
      int id = s_vidx[jj * 128 + arow];
      if (id >= 0) {
        w = s_attn[(jj * 128 + arow) * 8 + (c >> 5)];
        const float* src = fqkvV + (size_t)id * 256 + c;
        f0 = *(const float4*)src;
        f1 = *(const float4*)(src + 4);
      }
    } else if (c == 0) {
      f0.x = cell[q * 2]; f0.y = cell[q * 2 + 1];
      w = 64.f;
    }
  };

  frag_cd acc[4][4] = {};
  float4 f0c, f1c; float wc_;
  loadA(kbeg, f0c, f1c, wc_);
  const u16* bbase = Bt + (size_t)(tid >> 2) * KBIG + (tid & 3) * 8 + kbeg;
  u16* bdst = &Bs[(size_t)tid * 8];

  for (int k0 = kbeg; k0 < kend; k0 += BK) {
    glds16(bbase + (k0 - kbeg), bdst);
    glds16(bbase + (k0 - kbeg) + (size_t)128 * KBIG, bdst + 4096);
    {
      uint4 av;
      av.x = pk2(f0c.x * wc_, f0c.y * wc_);
      av.y = pk2(f0c.z * wc_, f0c.w * wc_);
      av.z = pk2(f1c.x * wc_, f1c.y * wc_);
      av.w = pk2(f1c.z * wc_, f1c.w * wc_);
      *(uint4*)&As[arow * LDSS + acol] = av;
    }
    __syncthreads();
    if (k0 + BK < kend) loadA(k0 + BK, f0c, f1c, wc_);
    frag_ab af[4];
    #pragma unroll
    for (int i = 0; i < 4; i++)
      af[i] = *(const frag_ab*)&As[(mw + i * 16 + lr) * LDSS + lk * 8];
    #pragma unroll
    for (int j = 0; j < 4; j++) {
      frag_ab bf = *(const frag_ab*)&Bs[(nwv + j * 16 + lr) * 32 + lk * 8];
      #pragma unroll
      for (int i = 0; i < 4; i++)
        acc[i][j] = __builtin_amdgcn_mfma_f32_16x16x32_bf16(af[i], bf, acc[i][j], 0, 0, 0);
    }
    __syncthreads();
  }

  #pragma unroll
  for (int i = 0; i < 4; i++)
    #pragma unroll
    for (int j = 0; j < 4; j++) {
      int col = nwv + j * 16 + lr;
      #pragma unroll
      for (int r = 0; r < 4; r++) {
        int row = m0 + mw + i * 16 + lk * 4 + r;
        P[(size_t)z * (NQ * 256) + (size_t)row * 256 + col] = f2b(acc[i][j][r]);
      }
    }
}

// ---------------------------------------------------------------------------
// Fused: hid2 = relu(sum_z Pb + bi1); out = bi2 + skip + hid2 . Wi2^T.
// ---------------------------------------------------------------------------
__global__ __launch_bounds__(256)
void reduce_final(const u16* __restrict__ Pb, const float* __restrict__ bi1,
                  const float* __restrict__ Wi2, const float* __restrict__ bi2,
                  const float* __restrict__ skipb, float* __restrict__ out)
{
  const int q = blockIdx.x, c = threadIdx.x;
  float s = 0.f;
  #pragma unroll
  for (int z = 0; z < SPLITK; z++)
    s += b2f(Pb[(size_t)z * (NQ * 256) + (size_t)q * 256 + c]);
  s += bi1[c];
  s = fmaxf(s, 0.f);

  __shared__ float part[3][4];
  float p0 = s * Wi2[c], p1 = s * Wi2[256 + c], p2 = s * Wi2[512 + c];
  #pragma unroll
  for (int off = 32; off; off >>= 1) {
    p0 += __shfl_xor(p0, off);
    p1 += __shfl_xor(p1, off);
    p2 += __shfl_xor(p2, off);
  }
  if ((c & 63) == 0) {
    int w = c >> 6;
    part[0][w] = p0; part[1][w] = p1; part[2][w] = p2;
  }
  __syncthreads();
  if (c < 3)
    out[q * 3 + c] = bi2[c] + skipb[q * 3 + c]
                   + part[c][0] + part[c][1] + part[c][2] + part[c][3];
}

// ---------------------------------------------------------------------------
// coord_mlp: rel(64x128) -> hid(64x256, relu) -> logits(64x49) -> softmax
// with attnval (per head), all in one block. grid 64, block 256.
// ---------------------------------------------------------------------------
__global__ __launch_bounds__(256)
void coord_mlp(const u16* __restrict__ relbuf, const u16* __restrict__ Btc1,
               const float* __restrict__ bc1, const float* __restrict__ Wc2,
               const float* __restrict__ bc2, float* __restrict__ attnval)
{
  __shared__ u16 smem[25600];            // 51.2 KB total
  u16*   s_rel = smem;                   // 64 x 136 bf16 (phase 1)
  u16*   s_hid = smem + 64 * 136;        // 64 x 264 bf16
  float* s_log = (float*)smem;           // 64 x 64 f32 (overlays s_rel)
  const int tid  = threadIdx.x;
  const int m0   = blockIdx.x * 64;
  const int wave = tid >> 6, lane = tid & 63;
  const int lr = lane & 15, lk = lane >> 4;

  #pragma unroll
  for (int e = 0; e < 2; e++) {
    int lin = tid + e * 256;
    int row = lin >> 4, c8 = (lin & 15) * 8;
    *(uint4*)&s_rel[row * 136 + c8] =
        *(const uint4*)&relbuf[(size_t)(m0 + row) * 128 + c8];
  }
  __syncthreads();

  // layer 1: hid = relu(rel @ Btc1^T + bc1); wave w -> cols w*64..+63
  {
    frag_cd acc[4][4] = {};
    const int nw = wave * 64;
    for (int kk = 0; kk < 4; kk++) {
      frag_ab af[4];
      #pragma unroll
      for (int i = 0; i < 4; i++)
        af[i] = *(const frag_ab*)&s_rel[(i * 16 + lr) * 136 + kk * 32 + lk * 8];
      #pragma unroll
      for (int t = 0; t < 4; t++) {
        int n = nw + t * 16 + lr;
        frag_ab bf = *(const frag_ab*)&Btc1[(size_t)n * 128 + kk * 32 + lk * 8];
        #pragma unroll
        for (int i = 0; i < 4; i++)
          acc[i][t] = __builtin_amdgcn_mfma_f32_16x16x32_bf16(af[i], bf, acc[i][t], 0, 0, 0);
      }
    }
    #pragma unroll
    for (int i = 0; i < 4; i++)
      #pragma unroll
      for (int t = 0; t < 4; t++) {
        int col = nw + t * 16 + lr;
        float badd = bc1[col];
        #pragma unroll
        for (int r = 0; r < 4; r++) {
          int row = i * 16 + lk * 4 + r;
          s_hid[row * 264 + col] = f2b(fmaxf(acc[i][t][r] + badd, 0.f));
        }
      }
  }
  __syncthreads();   // all waves done with s_rel + s_hid complete

  // layer 2: logits = hid @ Wc2^T + bc2; wave w -> cols w*16..+15 (pad >=49)
  {
    frag_cd acc[4] = {};
    const int nt = wave * 16;
    const int n = nt + lr;
    for (int kk = 0; kk < 8; kk++) {
      frag_ab bf;
      if (n < 49) {
        const float* wp = Wc2 + (size_t)n * 256 + kk * 32 + lk * 8;
        float4 w0 = *(const float4*)wp;
        float4 w1 = *(const float4*)(wp + 4);
        union { u16 s[8]; frag_ab f; } u;
        u.s[0] = f2b(w0.x); u.s[1] = f2b(w0.y); u.s[2] = f2b(w0.z); u.s[3] = f2b(w0.w);
        u.s[4] = f2b(w1.x); u.s[5] = f2b(w1.y); u.s[6] = f2b(w1.z); u.s[7] = f2b(w1.w);
        bf = u.f;
      } else {
        bf = frag_ab{0, 0, 0, 0, 0, 0, 0, 0};
      }
      #pragma unroll
      for (int i = 0; i < 4; i++) {
        frag_ab af = *(const frag_ab*)&s_hid[(i * 16 + lr) * 264 + kk * 32 + lk * 8];
        acc[i] = __builtin_amdgcn_mfma_f32_16x16x32_bf16(af, bf, acc[i], 0, 0, 0);
      }
    }
    const int col = nt + lr;
    const float badd = (col < 49) ? bc2[col] : 0.f;
    #pragma unroll
    for (int i = 0; i < 4; i++)
      #pragma unroll
      for (int r = 0; r < 4; r++) {
        int row = i * 16 + lk * 4 + r;
        s_log[row * 64 + col] = acc[i][r] + badd;
      }
  }
  __syncthreads();

  // softmax per (q,h) over 49 taps; attnval becomes the final weights.
  for (int p = tid; p < 512; p += 256) {
    int ql = p >> 3, h = p & 7;
    const size_t base = ((size_t)(m0 + ql) * 49) * 8 + h;
    float m = -1e30f;
    for (int j = 0; j < 49; j++) {
      float v = s_log[ql * 64 + j] + attnval[base + (size_t)j * 8];
      m = fmaxf(m, v);
    }
    float sum = 0.f;
    for (int j = 0; j < 49; j++) {
      float v = s_log[ql * 64 + j] + attnval[base + (size_t)j * 8];
      sum += expf(v - m);
    }
    float inv = 1.f / sum;
    for (int j = 0; j < 49; j++) {
      float v = s_log[ql * 64 + j] + attnval[base + (size_t)j * 8];
      attnval[base + (size_t)j * 8] = expf(v - m) * inv;
    }
  }
}

// ---------------------------------------------------------------------------
// Weight packing — single launch for everything.
// ---------------------------------------------------------------------------
static __device__ __forceinline__
void packconv(const float* __restrict__ W, u16* __restrict__ Bt,
              int Cin, int K2, int idx)
{
  int o  = idx / (Cin * K2);
  int r  = idx - o * (Cin * K2);
  int ci = r / K2;
  int s  = r - ci * K2;
  Bt[(size_t)o * (Cin * K2) + s * Cin + ci] = f2b(W[idx]);
}
static __device__ __forceinline__
void packcast(const float* __restrict__ W, u16* __restrict__ Bt,
              int Kin, int Kout, int idx)
{
  int n = idx / Kout, k = idx - n * Kout;
  Bt[idx] = f2b(k < Kin ? W[(size_t)n * Kin + k] : 0.f);
}

#define SZ_CH   147456   // 256*64*9
#define SZ_QKV  589824   // 256*256*9
#define SZ_OFF1 204800   // 256*32*25
#define SZ_OFF2 25088    // 98*256
#define SZ_C1   32768    // 256*128
#define SZ_WI1  3219456  // 256*12576
#define SZ_PACK (SZ_CH + 3*SZ_QKV + SZ_OFF1 + SZ_OFF2 + SZ_C1 + 768 + SZ_WI1)

__global__ void pack_all(const float* W_ch, const float* W_q, const float* W_k,
                         const float* W_v, const float* W_off1, const float* W_off2,
                         const float* Wc1, const float* Wi1,
                         const float* b_q, const float* b_k, const float* b_v,
                         u16* Btch, u16* Btqkv, u16* Btoff1, u16* Btoff2,
                         u16* Btc1, u16* Wi1p, float* bqkv)
{
  int i = blockIdx.x * 256 + threadIdx.x;
  if (i < SZ_CH) { packconv(W_ch, Btch, 64, 9, i); return; }
  i -= SZ_CH;
  if (i < SZ_QKV) { packconv(W_q, Btqkv, 256, 9, i); return; }
  i -= SZ_QKV;
  if (i < SZ_QKV) { packconv(W_k, Btqkv + (size_t)256 * 2304, 256, 9, i); return; }
  i -= SZ_QKV;
  if (i < SZ_QKV) { packconv(W_v, Btqkv + (size_t)512 * 2304, 256, 9, i); return; }
  i -= SZ_QKV;
  if (i < SZ_OFF1) { packconv(W_off1, Btoff1, 32, 25, i); return; }
  i -= SZ_OFF1;
  if (i < SZ_OFF2) { packcast(W_off2, Btoff2, 256, 256, i); return; }
  i -= SZ_OFF2;
  if (i < SZ_C1) { packcast(Wc1, Btc1, 98, 128, i); return; }
  i -= SZ_C1;
  if (i < 768) {
    bqkv[i] = (i < 256) ? b_q[i] : (i < 512) ? b_k[i - 256] : b_v[i - 512];
    return;
  }
  i -= 768;
  if (i < SZ_WI1) { packcast(Wi1, Wi1p, 12546, 12576, i); }
}

// ---------------------------------------------------------------------------
// Encoder conv: 3->64, 3x3 pad1, +bias, relu -> feat1 (HW,64) bf16
// ---------------------------------------------------------------------------
__global__ __launch_bounds__(64)
void conv_enc(const float* __restrict__ inp, const float* __restrict__ W,
              const float* __restrict__ b, u16* __restrict__ feat1)
{
  const int p = blockIdx.x, c = threadIdx.x;
  const int y = p >> 6, x = p & 63;
  float s = b[c];
  #pragma unroll
  for (int ci = 0; ci < 3; ci++)
    #pragma unroll
    for (int dy = 0; dy < 3; dy++) {
      int yy = y + dy - 1;
      if ((unsigned)yy >= 64u) continue;
      #pragma unroll
      for (int dx = 0; dx < 3; dx++) {
        int xx = x + dx - 1;
        if ((unsigned)xx >= 64u) continue;
        s += inp[ci * HW + yy * 64 + xx] * W[((c * 3 + ci) * 3 + dy) * 3 + dx];
      }
    }
  feat1[(size_t)p * 64 + c] = f2b(fmaxf(s, 0.f));
}

// ---------------------------------------------------------------------------
// LayerNorm(channel) + exact GELU
// ---------------------------------------------------------------------------
__global__ __launch_bounds__(256)
void ln_gelu(const float* __restrict__ x, const float* __restrict__ g,
             const float* __restrict__ b, u16* __restrict__ y)
{
  const int p = blockIdx.x, c = threadIdx.x;
  __shared__ float r1[4], r2[4];
  float v = x[(size_t)p * 256 + c];
  float s1 = v, s2 = v * v;
  #pragma unroll
  for (int off = 32; off; off >>= 1) {
    s1 += __shfl_xor(s1, off);
    s2 += __shfl_xor(s2, off);
  }
  if ((c & 63) == 0) { r1[c >> 6] = s1; r2[c >> 6] = s2; }
  __syncthreads();
  float t1 = r1[0] + r1[1] + r1[2] + r1[3];
  float t2 = r2[0] + r2[1] + r2[2] + r2[3];
  float mu  = t1 * (1.f / 256.f);
  float var = t2 * (1.f / 256.f) - mu * mu;
  float xn = (v - mu) * rsqrtf(var + 1e-5f) * g[c] + b[c];
  float ge = 0.5f * xn * (1.f + erff(xn * 0.70710678118654752f));
  y[(size_t)p * 256 + c] = f2b(ge);
}

// ---------------------------------------------------------------------------
// Per-query sampler (writes raw q.k dots to attnval; coord_mlp finalizes).
// ---------------------------------------------------------------------------
__global__ __launch_bounds__(256)
void sampler(const float* __restrict__ coord, const u16* __restrict__ fqkvb,
             const float* __restrict__ offs, const float* __restrict__ inp,
             float* __restrict__ attnval, u16* __restrict__ relbuf,
             int* __restrict__ vidx, float* __restrict__ skipb)
{
  const int q = blockIdx.x;
  const int tid = threadIdx.x;
  __shared__ float s_off[98];
  __shared__ int s_idx[49];
  __shared__ float s_q[256];

  const float c0 = coord[q * 2], c1 = coord[q * 2 + 1];
  const float gxp = ((c1 + 1.f) * 64.f - 1.f) * 0.5f;
  const float gyp = ((c0 + 1.f) * 64.f - 1.f) * 0.5f;
  const int ixn = (int)rintf(gxp), iyn = (int)rintf(gyp);
  const bool inn = ((unsigned)ixn < 64u) && ((unsigned)iyn < 64u);

  if (tid < 98) {
    float v = inn ? offs[(size_t)(iyn * 64 + ixn) * 98 + tid] : 0.f;
    s_off[tid] = tanhf(v) * (2.f / 63.f);
  }
  __syncthreads();

  const float scky = inn ? (-1.f + (float)(2 * iyn + 1) * (1.f / 64.f)) : 0.f;
  const float sckx = inn ? (-1.f + (float)(2 * ixn + 1) * (1.f / 64.f)) : 0.f;

  if (tid < 49) {
    const int a = tid / 7, bb = tid - a * 7;
    float sy = scky + (float)(a - 3) * (2.f / 64.f) + s_off[2 * tid];
    float sx = sckx + (float)(bb - 3) * (2.f / 64.f) + s_off[2 * tid + 1];
    relbuf[(size_t)q * 128 + 2 * tid]     = f2b((c0 - sy) * 64.f);
    relbuf[(size_t)q * 128 + 2 * tid + 1] = f2b((c1 - sx) * 64.f);
    float gx2 = ((sx + 1.f) * 64.f - 1.f) * 0.5f;
    float gy2 = ((sy + 1.f) * 64.f - 1.f) * 0.5f;
    int ix2 = (int)rintf(gx2), iy2 = (int)rintf(gy2);
    int id = (((unsigned)ix2 < 64u) && ((unsigned)iy2 < 64u)) ? (iy2 * 64 + ix2) : -1;
    s_idx[tid] = id;
    vidx[q * 49 + tid] = id;
  } else if (tid >= 98 && tid < 128) {
    relbuf[(size_t)q * 128 + tid] = 0;
  }

  {
    const float x0f = floorf(gxp), y0f = floorf(gyp);
    const float wx = gxp - x0f, wy = gyp - y0f;
    const int x0 = (int)x0f, y0 = (int)y0f;
    float qc = 0.f;
    #pragma unroll
    for (int t = 0; t < 4; t++) {
      int xi = x0 + (t & 1), yi = y0 + (t >> 1);
      if (((unsigned)xi < 64u) && ((unsigned)yi < 64u)) {
        float w = ((t & 1) ? wx : 1.f - wx) * ((t >> 1) ? wy : 1.f - wy);
        qc += w * b2f(fqkvb[(size_t)(yi * 64 + xi) * 768 + tid]);
      }
    }
    s_q[tid] = qc * 0.17677669529663687f;
  }

  if (tid < 3) {
    float gx = fminf(fmaxf(gxp, 0.f), 63.f);
    float gy = fminf(fmaxf(gyp, 0.f), 63.f);
    float xf = floorf(gx), yf = floorf(gy);
    float wxs = gx - xf, wys = gy - yf;
    int xa = (int)xf, ya = (int)yf;
    int xb = min(xa + 1, 63), yb = min(ya + 1, 63);
    const float* ch = inp + tid * HW;
    float v = (1.f - wxs) * (1.f - wys) * ch[ya * 64 + xa]
            + wxs * (1.f - wys) * ch[ya * 64 + xb]
            + (1.f - wxs) * wys * ch[yb * 64 + xa]
            + wxs * wys * ch[yb * 64 + xb];
    skipb[q * 3 + tid] = v;
  }
  __syncthreads();

  const int wave = tid >> 6, lane = tid & 63;
  const int half = lane >> 5, sub = lane & 31;
  const int ch0 = sub * 8;
  const int h = sub >> 2;
  float qv[8];
  #pragma unroll
  for (int i = 0; i < 8; i++) qv[i] = s_q[ch0 + i];

  for (int it = 0; it < 7; it++) {
    int j = it * 8 + wave * 2 + half;
    if (j >= 49) break;
    int id = s_idx[j];
    float p = 0.f;
    if (id >= 0) {
      uint4 kv = *(const uint4*)&fqkvb[(size_t)id * 768 + 256 + ch0];
      u32 w0 = kv.x, w1 = kv.y, w2 = kv.z, w3 = kv.w;
      p = fmaf(qv[0], __uint_as_float(w0 << 16), p);
      p = fmaf(qv[1], __uint_as_float(w0 & 0xffff0000u), p);
      p = fmaf(qv[2], __uint_as_float(w1 << 16), p);
      p = fmaf(qv[3], __uint_as_float(w1 & 0xffff0000u), p);
      p = fmaf(qv[4], __uint_as_float(w2 << 16), p);
      p = fmaf(qv[5], __uint_as_float(w2 & 0xffff0000u), p);
      p = fmaf(qv[6], __uint_as_float(w3 << 16), p);
      p = fmaf(qv[7], __uint_as_float(w3 & 0xffff0000u), p);
    }
    p += __shfl_down(p, 2, 4);
    p += __shfl_down(p, 1, 4);
    if ((sub & 3) == 0) attnval[((size_t)q * 49 + j) * 8 + h] = p;
  }
}

// ===========================================================================
extern "C" void kernel_launch(void* const* d_in, const int* in_sizes, int n_in,
                              void* d_out, int out_size, void* d_ws, size_t ws_size,
                              hipStream_t stream)
{
  const float* inp    = (const float*)d_in[0];
  const float* coord  = (const float*)d_in[1];
  const float* cell   = (const float*)d_in[2];
  const float* W_enc  = (const float*)d_in[3];
  const float* b_enc  = (const float*)d_in[4];
  const float* W_ch   = (const float*)d_in[5];
  const float* b_ch   = (const float*)d_in[6];
  const float* W_q    = (const float*)d_in[7];
  const float* b_q    = (const float*)d_in[8];
  const float* W_k    = (const float*)d_in[9];
  const float* b_k    = (const float*)d_in[10];
  const float* W_v    = (const float*)d_in[11];
  const float* b_v    = (const float*)d_in[12];
  const float* W_off1 = (const float*)d_in[13];
  const float* b_off1 = (const float*)d_in[14];
  const float* ln_g   = (const float*)d_in[15];
  const float* ln_b   = (const float*)d_in[16];
  const float* W_off2 = (const float*)d_in[17];
  const float* Wc1    = (const float*)d_in[18];
  const float* bc1    = (const float*)d_in[19];
  const float* Wc2    = (const float*)d_in[20];
  const float* bc2    = (const float*)d_in[21];
  const float* Wi1    = (const float*)d_in[22];
  const float* bi1    = (const float*)d_in[23];
  const float* Wi2    = (const float*)d_in[24];
  const float* bi2    = (const float*)d_in[25];

  char* base = (char*)d_ws;
  size_t off = 0;
  auto alloc = [&](size_t bytes) -> char* {
    char* r = base + off;
    off = (off + bytes + 255) & ~(size_t)255;
    return r;
  };

  // --- scratch region (dead before gemm_big runs; Pb aliases it) ---
  float* obuf   = (float*)alloc((size_t)HW * 256 * 4);
  u16*   ocg    = (u16*)  alloc((size_t)HW * 256 * 2);
  float* offsb  = (float*)alloc((size_t)HW * 98 * 4);
  u16*   feat1  = (u16*)  alloc((size_t)HW * 64 * 2);
  u16*   feat   = (u16*)  alloc((size_t)HW * 256 * 2);
  u16*   relbuf = (u16*)  alloc((size_t)NQ * 128 * 2);
  u16*   Btqkv  = (u16*)  alloc((size_t)768 * 2304 * 2);
  u16*   Btch   = (u16*)  alloc((size_t)256 * 576 * 2);
  u16*   Btoff1 = (u16*)  alloc((size_t)256 * 800 * 2);
  u16*   Btoff2 = (u16*)  alloc((size_t)98 * 256 * 2);
  u16*   Btc1   = (u16*)  alloc((size_t)256 * 128 * 2);
  // gemm_big bf16 partials alias scratch: 16 x 2MB = 33.6MB at base+0.
  u16* Pb = (u16*)base;
  // qkv bf16 partials at [36MB, 54.9MB): past live scratch (~18MB),
  // disjoint from Pb's 33.6MB, dead before gemm_big.
  u16* Pqb = (u16*)(base + ((size_t)36 << 20));
  {
    size_t need = ((size_t)36 << 20) + (size_t)QSPLIT * NQ * 768 * 2;
    if (off < need) off = (need + 255) & ~(size_t)255;
  }
  // --- persistent buffers ---
  u16*   fqkvb   = (u16*)  alloc((size_t)HW * 768 * 2);
  float* fqkvV   = (float*)alloc((size_t)HW * 256 * 4);
  float* attnval = (float*)alloc((size_t)NQ * 49 * 8 * 4);
  int*   vidxb   = (int*)  alloc((size_t)NQ * 49 * 4);
  float* skipb   = (float*)alloc((size_t)NQ * 3 * 4);
  u16*   Wi1p    = (u16*)  alloc((size_t)256 * KBIG * 2);
  float* bqkv    = (float*)alloc(768 * 4);
  (void)ws_size; (void)in_sizes; (void)n_in; (void)out_size;

  // --- weight packing (single launch) ---
  pack_all<<<(SZ_PACK + 255) / 256, 256, 0, stream>>>(
      W_ch, W_q, W_k, W_v, W_off1, W_off2, Wc1, Wi1, b_q, b_k, b_v,
      Btch, Btqkv, Btoff1, Btoff2, Btc1, Wi1p, bqkv);

  // --- conv stack (implicit im2col) ---
  conv_enc<<<HW, 64, 0, stream>>>(inp, W_enc, b_enc, feat1);
  gemm_conv<3, 6, 1><<<dim3(64, 4, 1), 256, 0, stream>>>(
      feat1, Btch, feat, b_ch, 256, 576, 256, /*bf16*/2, 64, 0, 0, 0, 0);
  gemm_qkv<<<dim3(64, 6, QSPLIT), 256, 0, stream>>>(feat, Btqkv, Pqb);
  reduce_qkv<<<(NQ * 96 + 255) / 256, 256, 0, stream>>>(Pqb, bqkv, fqkvb, fqkvV);
  gemm_conv<5, 5, 2><<<dim3(64, 1, 8), 256, 0, stream>>>(
      feat, Btoff1, obuf, b_off1, 32, 800, 256, 0, 256, 32,
      (long)32 * 800, 32, 32);
  ln_gelu<<<HW, 256, 0, stream>>>(obuf, ln_g, ln_b, ocg);
  gemm_bt<<<dim3(64, 2, 1), 256, 0, stream>>>(ocg, Btoff2, offsb, nullptr,
      98, 256, 98, 0, 0, 0, 0, 0);

  // --- per-query attention path ---
  sampler<<<NQ, 256, 0, stream>>>(coord, fqkvb, offsb, inp,
                                  attnval, relbuf, vidxb, skipb);
  coord_mlp<<<64, 256, 0, stream>>>(relbuf, Btc1, bc1, Wc2, bc2, attnval);

  // --- big MLP: 128x256 tile, gather-A, glds-B, split-K(16), bf16 P ---
  gemm_big<<<dim3(32, SPLITK), 512, 0, stream>>>(
      Wi1p, fqkvV, attnval, vidxb, cell, Pb);
  reduce_final<<<NQ, 256, 0, stream>>>(Pb, bi1, Wi2, bi2, skipb, (float*)d_out);
}

// Round 13
// 290.483 us; speedup vs baseline: 1.1253x; 1.1253x over previous
//
#include <hip/hip_runtime.h>
#include <hip/hip_bf16.h>

// ============================================================================
// IDASR pipeline on gfx950 — round 13.
// Change vs round 12: REVERT coord_mlp (58us, 64-block latency disaster:
// Occ 2.4%, serial softmax passes) back to round-11's 3-kernel chain
// (gemm_bt c1 -> gemm_bt c2 -> softmax_k). Keep pack_all + QSPLIT=3.
// ============================================================================

typedef unsigned short u16;
typedef unsigned int u32;
using frag_ab = __attribute__((ext_vector_type(8))) short;  // 8 x bf16
using frag_cd = __attribute__((ext_vector_type(4))) float;  // 4 x f32 acc

#define HW 4096
#define NQ 4096
#define KBIG 12576
#define SPLITK 16
#define KCHUNK 800
#define KQ 2304
#define QSPLIT 3
#define QCHUNK 768

static __device__ __forceinline__ u16 f2b(float f) {
  union { __hip_bfloat16 h; u16 u; } c; c.h = __float2bfloat16(f); return c.u;
}
static __device__ __forceinline__ float b2f(u16 v) {
  return __uint_as_float((u32)v << 16);
}
static __device__ __forceinline__ u32 pk2(float a, float b) {
  union { __hip_bfloat162 h; u32 u; } c;
  c.h = __float22bfloat162_rn(float2{a, b});
  return c.u;
}
// async global->LDS, 16B per lane. LDS dest is wave-uniform base + lane*16.
static __device__ __forceinline__ void glds16(const u16* g, u16* l) {
  __builtin_amdgcn_global_load_lds(
      (const __attribute__((address_space(1))) u32*)(g),
      (__attribute__((address_space(3))) u32*)(l), 16, 0, 0);
}

#define BM 64
#define BN 64
#define BK 32
#define LDSS 40   // padded lds row stride for reg-staged tiles

// ---------------------------------------------------------------------------
// Generic bf16 GEMM (64x64 tile): off2, c1, c2 layers.
// ---------------------------------------------------------------------------
__global__ __launch_bounds__(256)
void gemm_bt(const u16* __restrict__ A, const u16* __restrict__ Bt,
             void* __restrict__ Cv, const float* __restrict__ bias,
             int N, int K, int ldc, int flags,   // 1=relu, 2=bf16 out
             long sA, long sB, long sC, int sBias)
{
  __shared__ u16 As[BM * LDSS];
  __shared__ u16 Bs[BN * LDSS];
  const int z = blockIdx.z;
  A  += (long)z * sA;
  Bt += (long)z * sB;
  const float* bz = bias ? bias + (long)z * sBias : nullptr;

  const int tid  = threadIdx.x;
  const int m0   = blockIdx.x * BM;
  const int n0   = blockIdx.y * BN;
  const int wave = tid >> 6, lane = tid & 63;
  const int mw = (wave & 1) * 32, nw = (wave >> 1) * 32;
  const int lr = lane & 15, lk = lane >> 4;
  const int srow = tid >> 2, scol = (tid & 3) * 8;

  frag_cd acc[2][2] = {};
  const u16* aptr = A + (size_t)(m0 + srow) * K + scol;
  const bool bok  = (n0 + srow) < N;
  const u16* bptr = Bt + (size_t)(n0 + srow) * K + scol;

  uint4 av = *(const uint4*)(aptr);
  uint4 bv = bok ? *(const uint4*)(bptr) : uint4{0u, 0u, 0u, 0u};

  for (int k0 = 0; k0 < K; k0 += BK) {
    *(uint4*)&As[srow * LDSS + scol] = av;
    *(uint4*)&Bs[srow * LDSS + scol] = bv;
    __syncthreads();
    if (k0 + BK < K) {
      av = *(const uint4*)(aptr + k0 + BK);
      bv = bok ? *(const uint4*)(bptr + k0 + BK) : uint4{0u, 0u, 0u, 0u};
    }
    frag_ab af0 = *(const frag_ab*)&As[(mw      + lr) * LDSS + lk * 8];
    frag_ab af1 = *(const frag_ab*)&As[(mw + 16 + lr) * LDSS + lk * 8];
    frag_ab bf0 = *(const frag_ab*)&Bs[(nw      + lr) * LDSS + lk * 8];
    frag_ab bf1 = *(const frag_ab*)&Bs[(nw + 16 + lr) * LDSS + lk * 8];
    acc[0][0] = __builtin_amdgcn_mfma_f32_16x16x32_bf16(af0, bf0, acc[0][0], 0, 0, 0);
    acc[0][1] = __builtin_amdgcn_mfma_f32_16x16x32_bf16(af0, bf1, acc[0][1], 0, 0, 0);
    acc[1][0] = __builtin_amdgcn_mfma_f32_16x16x32_bf16(af1, bf0, acc[1][0], 0, 0, 0);
    acc[1][1] = __builtin_amdgcn_mfma_f32_16x16x32_bf16(af1, bf1, acc[1][1], 0, 0, 0);
    __syncthreads();
  }

  const bool relu = flags & 1;
  const bool obf  = flags & 2;
  #pragma unroll
  for (int i = 0; i < 2; i++)
    #pragma unroll
    for (int j = 0; j < 2; j++) {
      int col = n0 + nw + j * 16 + lr;
      if (col >= N) continue;
      float badd = bz ? bz[col] : 0.f;
      #pragma unroll
      for (int r = 0; r < 4; r++) {
        int row = m0 + mw + i * 16 + lk * 4 + r;
        float v = acc[i][j][r] + badd;
        if (relu) v = fmaxf(v, 0.f);
        size_t idx = (size_t)z * sC + (size_t)row * ldc + col;
        if (obf) ((u16*)Cv)[idx] = f2b(v);
        else     ((float*)Cv)[idx] = v;
      }
    }
}

// ---------------------------------------------------------------------------
// Implicit-im2col conv GEMM, 64x64 tile (ch conv, grouped off1 conv).
// ---------------------------------------------------------------------------
template<int W3, int SH, int PAD>
__global__ __launch_bounds__(256)
void gemm_conv(const u16* __restrict__ feat, const u16* __restrict__ Bt,
               void* __restrict__ Cv, const float* __restrict__ bias,
               int N, int K, int ldc, int flags, int FC, int cbStride,
               long sB, long sC, int sBias)
{
  __shared__ u16 As[BM * LDSS];
  __shared__ u16 Bs[BN * LDSS];
  const int z = blockIdx.z;
  Bt += (long)z * sB;
  const float* bz = bias ? bias + (long)z * sBias : nullptr;
  const int cb = z * cbStride;

  const int tid  = threadIdx.x;
  const int m0   = blockIdx.x * BM;
  const int n0   = blockIdx.y * BN;
  const int wave = tid >> 6, lane = tid & 63;
  const int mw = (wave & 1) * 32, nw = (wave >> 1) * 32;
  const int lr = lane & 15, lk = lane >> 4;
  const int srow = tid >> 2, scol = (tid & 3) * 8;
  const int p = m0 + srow, y = p >> 6, x = p & 63;

  frag_cd acc[2][2] = {};
  const bool bok  = (n0 + srow) < N;
  const u16* bptr = Bt + (size_t)(n0 + srow) * K + scol;

  auto stageA = [&](int k0) -> uint4 {
    int k = k0 + scol;
    int s = k >> SH;
    int c = k & ((1 << SH) - 1);
    int dy = s / W3, dx = s - dy * W3;
    int yy = y + dy - PAD, xx = x + dx - PAD;
    if (((unsigned)yy < 64u) && ((unsigned)xx < 64u))
      return *(const uint4*)&feat[(size_t)(yy * 64 + xx) * FC + cb + c];
    return uint4{0u, 0u, 0u, 0u};
  };

  uint4 av = stageA(0);
  uint4 bv = bok ? *(const uint4*)(bptr) : uint4{0u, 0u, 0u, 0u};

  for (int k0 = 0; k0 < K; k0 += BK) {
    *(uint4*)&As[srow * LDSS + scol] = av;
    *(uint4*)&Bs[srow * LDSS + scol] = bv;
    __syncthreads();
    if (k0 + BK < K) {
      av = stageA(k0 + BK);
      bv = bok ? *(const uint4*)(bptr + k0 + BK) : uint4{0u, 0u, 0u, 0u};
    }
    frag_ab af0 = *(const frag_ab*)&As[(mw      + lr) * LDSS + lk * 8];
    frag_ab af1 = *(const frag_ab*)&As[(mw + 16 + lr) * LDSS + lk * 8];
    frag_ab bf0 = *(const frag_ab*)&Bs[(nw      + lr) * LDSS + lk * 8];
    frag_ab bf1 = *(const frag_ab*)&Bs[(nw + 16 + lr) * LDSS + lk * 8];
    acc[0][0] = __builtin_amdgcn_mfma_f32_16x16x32_bf16(af0, bf0, acc[0][0], 0, 0, 0);
    acc[0][1] = __builtin_amdgcn_mfma_f32_16x16x32_bf16(af0, bf1, acc[0][1], 0, 0, 0);
    acc[1][0] = __builtin_amdgcn_mfma_f32_16x16x32_bf16(af1, bf0, acc[1][0], 0, 0, 0);
    acc[1][1] = __builtin_amdgcn_mfma_f32_16x16x32_bf16(af1, bf1, acc[1][1], 0, 0, 0);
    __syncthreads();
  }

  const bool relu = flags & 1;
  const bool obf  = flags & 2;
  #pragma unroll
  for (int i = 0; i < 2; i++)
    #pragma unroll
    for (int j = 0; j < 2; j++) {
      int col = n0 + nw + j * 16 + lr;
      if (col >= N) continue;
      float badd = bz ? bz[col] : 0.f;
      #pragma unroll
      for (int r = 0; r < 4; r++) {
        int row = m0 + mw + i * 16 + lk * 4 + r;
        float v = acc[i][j][r] + badd;
        if (relu) v = fmaxf(v, 0.f);
        size_t idx = (size_t)z * sC + (size_t)row * ldc + col;
        if (obf) ((u16*)Cv)[idx] = f2b(v);
        else     ((float*)Cv)[idx] = v;
      }
    }
}

// ---------------------------------------------------------------------------
// qkv conv GEMM: implicit im2col A, glds-B, split-K(3), bf16 partials.
// Tile 64x128, grid (64, 6, 3). Partials -> Pqb[z][row][col] (bf16).
// ---------------------------------------------------------------------------
__global__ __launch_bounds__(256)
void gemm_qkv(const u16* __restrict__ feat, const u16* __restrict__ Bt,
              u16* __restrict__ P)
{
  __shared__ u16 As[64 * LDSS];   // padded, reg-staged
  __shared__ u16 Bs[128 * 32];    // unpadded, glds target
  const int tid  = threadIdx.x;
  const int m0   = blockIdx.x * 64;
  const int n0   = blockIdx.y * 128;
  const int z    = blockIdx.z;
  const int kbeg = z * QCHUNK;
  const int kend = kbeg + QCHUNK;
  const int wave = tid >> 6, lane = tid & 63;
  const int nw = wave * 32;
  const int lr = lane & 15, lk = lane >> 4;
  const int arow = tid >> 2, acol = (tid & 3) * 8;
  const int p = m0 + arow, y = p >> 6, x = p & 63;

  frag_cd acc[4][2] = {};
  const u16* bbase = Bt + (size_t)(n0 + (tid >> 2)) * KQ + (tid & 3) * 8 + kbeg;
  u16* bdst = &Bs[(size_t)tid * 8];

  auto stageA = [&](int k0) -> uint4 {
    int k = k0 + acol;
    int s = k >> 8, c = k & 255;
    int dy = s / 3, dx = s - dy * 3;
    int yy = y + dy - 1, xx = x + dx - 1;
    if (((unsigned)yy < 64u) && ((unsigned)xx < 64u))
      return *(const uint4*)&feat[(size_t)(yy * 64 + xx) * 256 + c];
    return uint4{0u, 0u, 0u, 0u};
  };

  uint4 av = stageA(kbeg);

  for (int k0 = kbeg; k0 < kend; k0 += BK) {
    glds16(bbase + (k0 - kbeg), bdst);
    glds16(bbase + (k0 - kbeg) + (size_t)64 * KQ, bdst + 2048);
    *(uint4*)&As[arow * LDSS + acol] = av;
    __syncthreads();
    if (k0 + BK < kend) av = stageA(k0 + BK);
    frag_ab af[4];
    #pragma unroll
    for (int i = 0; i < 4; i++)
      af[i] = *(const frag_ab*)&As[(i * 16 + lr) * LDSS + lk * 8];
    #pragma unroll
    for (int j = 0; j < 2; j++) {
      frag_ab bf = *(const frag_ab*)&Bs[(nw + j * 16 + lr) * 32 + lk * 8];
      #pragma unroll
      for (int i = 0; i < 4; i++)
        acc[i][j] = __builtin_amdgcn_mfma_f32_16x16x32_bf16(af[i], bf, acc[i][j], 0, 0, 0);
    }
    __syncthreads();
  }

  #pragma unroll
  for (int i = 0; i < 4; i++)
    #pragma unroll
    for (int j = 0; j < 2; j++) {
      int col = n0 + nw + j * 16 + lr;
      #pragma unroll
      for (int r = 0; r < 4; r++) {
        int row = m0 + i * 16 + lk * 4 + r;
        P[(size_t)z * (NQ * 768) + (size_t)row * 768 + col] = f2b(acc[i][j][r]);
      }
    }
}

// sum QSPLIT bf16 qkv partials + bias -> fqkvb (bf16) and fqkvV (f32 V).
__global__ __launch_bounds__(256)
void reduce_qkv(const u16* __restrict__ P, const float* __restrict__ bias,
                u16* __restrict__ outb, float* __restrict__ outV)
{
  int i8 = blockIdx.x * 256 + threadIdx.x;
  if (i8 >= NQ * 96) return;
  size_t i = (size_t)i8 * 8;
  int row = (int)(i / 768);
  int c = (int)(i % 768);
  float v[8];
  #pragma unroll
  for (int t = 0; t < 8; t++) v[t] = bias[c + t];
  for (int z = 0; z < QSPLIT; z++) {
    uint4 a = *(const uint4*)&P[(size_t)z * (NQ * 768) + i];
    u32 aw[4] = {a.x, a.y, a.z, a.w};
    #pragma unroll
    for (int t = 0; t < 4; t++) {
      v[2 * t]     += __uint_as_float(aw[t] << 16);
      v[2 * t + 1] += __uint_as_float(aw[t] & 0xffff0000u);
    }
  }
  uint4 ob = {pk2(v[0], v[1]), pk2(v[2], v[3]), pk2(v[4], v[5]), pk2(v[6], v[7])};
  *(uint4*)&outb[i] = ob;
  if (c >= 512) {
    float* dst = outV + (size_t)row * 256 + (c - 512);
    *(float4*)dst       = float4{v[0], v[1], v[2], v[3]};
    *(float4*)(dst + 4) = float4{v[4], v[5], v[6], v[7]};
  }
}

// ---------------------------------------------------------------------------
// Big MLP GEMM: fused gather-A (f32 V, deferred pack), 128x256 tile, glds-B,
// split-K(16), bf16 partials. block 512 (8 waves), grid (32, 16) = 2/CU.
// ---------------------------------------------------------------------------
__global__ __launch_bounds__(512, 4)
void gemm_big(const u16* __restrict__ Bt, const float* __restrict__ fqkvV,
              const float* __restrict__ attnval, const int* __restrict__ vidx,
              const float* __restrict__ cell, u16* __restrict__ P)
{
  __shared__ u16 As[128 * LDSS];         // 10 KB padded, reg-staged gather
  __shared__ u16 Bs[256 * 32];           // 16 KB unpadded, glds target
  __shared__ int   s_vidx[5 * 128];      // 2.5 KB
  __shared__ float s_attn[5 * 128 * 8];  // 20 KB
  const int tid  = threadIdx.x;
  const int m0   = blockIdx.x * 128;
  const int z    = blockIdx.y;
  const int kbeg = z * KCHUNK;
  const int kend = min(KBIG, kbeg + KCHUNK);
  const int jbeg = kbeg >> 8;
  const int jcnt = ((kend - 1) >> 8) - jbeg + 1;   // <= 5
  const int wave = tid >> 6, lane = tid & 63;
  const int mw = (wave & 1) * 64, nwv = (wave >> 1) * 64;
  const int lr = lane & 15, lk = lane >> 4;
  const int arow = tid >> 2, acol = (tid & 3) * 8;  // 128 rows x 4x8
  const int q = m0 + arow;

  for (int t = tid; t < 128 * jcnt; t += 512) {
    int r = t & 127, jj = t >> 7;
    int j = jbeg + jj;
    s_vidx[t] = (j < 49) ? vidx[(m0 + r) * 49 + j] : -1;
  }
  for (int t = tid; t < 128 * 8 * jcnt; t += 512) {
    int h = t & 7, rr = (t >> 3) & 127, jj = t >> 10;
    int j = jbeg + jj;
    s_attn[t] = (j < 49) ? attnval[((size_t)((m0 + rr) * 49 + j)) * 8 + h] : 0.f;
  }
  __syncthreads();

  auto loadA = [&](int k0, float4& f0, float4& f1, float& w) {
    const int k = k0 + acol;
    const int j = k >> 8, c = k & 255;
    f0 = float4{0.f, 0.f, 0.f, 0.f};
    f1 = float4{0.f, 0.f, 0.f, 0.f};
    w = 0.f;
    if (j < 49) {
      const int jj = j - jbeg;
      int id = s_vidx[jj * 128 + arow];
      if (id >= 0) {
        w = s_attn[(jj * 128 + arow) * 8 + (c >> 5)];
        const float* src = fqkvV + (size_t)id * 256 + c;
        f0 = *(const float4*)src;
        f1 = *(const float4*)(src + 4);
      }
    } else if (c == 0) {
      f0.x = cell[q * 2]; f0.y = cell[q * 2 + 1];
      w = 64.f;
    }
  };

  frag_cd acc[4][4] = {};
  float4 f0c, f1c; float wc_;
  loadA(kbeg, f0c, f1c, wc_);
  const u16* bbase = Bt + (size_t)(tid >> 2) * KBIG + (tid & 3) * 8 + kbeg;
  u16* bdst = &Bs[(size_t)tid * 8];

  for (int k0 = kbeg; k0 < kend; k0 += BK) {
    glds16(bbase + (k0 - kbeg), bdst);
    glds16(bbase + (k0 - kbeg) + (size_t)128 * KBIG, bdst + 4096);
    {
      uint4 av;
      av.x = pk2(f0c.x * wc_, f0c.y * wc_);
      av.y = pk2(f0c.z * wc_, f0c.w * wc_);
      av.z = pk2(f1c.x * wc_, f1c.y * wc_);
      av.w = pk2(f1c.z * wc_, f1c.w * wc_);
      *(uint4*)&As[arow * LDSS + acol] = av;
    }
    __syncthreads();
    if (k0 + BK < kend) loadA(k0 + BK, f0c, f1c, wc_);
    frag_ab af[4];
    #pragma unroll
    for (int i = 0; i < 4; i++)
      af[i] = *(const frag_ab*)&As[(mw + i * 16 + lr) * LDSS + lk * 8];
    #pragma unroll
    for (int j = 0; j < 4; j++) {
      frag_ab bf = *(const frag_ab*)&Bs[(nwv + j * 16 + lr) * 32 + lk * 8];
      #pragma unroll
      for (int i = 0; i < 4; i++)
        acc[i][j] = __builtin_amdgcn_mfma_f32_16x16x32_bf16(af[i], bf, acc[i][j], 0, 0, 0);
    }
    __syncthreads();
  }

  #pragma unroll
  for (int i = 0; i < 4; i++)
    #pragma unroll
    for (int j = 0; j < 4; j++) {
      int col = nwv + j * 16 + lr;
      #pragma unroll
      for (int r = 0; r < 4; r++) {
        int row = m0 + mw + i * 16 + lk * 4 + r;
        P[(size_t)z * (NQ * 256) + (size_t)row * 256 + col] = f2b(acc[i][j][r]);
      }
    }
}

// ---------------------------------------------------------------------------
// Fused: hid2 = relu(sum_z Pb + bi1); out = bi2 + skip + hid2 . Wi2^T.
// ---------------------------------------------------------------------------
__global__ __launch_bounds__(256)
void reduce_final(const u16* __restrict__ Pb, const float* __restrict__ bi1,
                  const float* __restrict__ Wi2, const float* __restrict__ bi2,
                  const float* __restrict__ skipb, float* __restrict__ out)
{
  const int q = blockIdx.x, c = threadIdx.x;
  float s = 0.f;
  #pragma unroll
  for (int z = 0; z < SPLITK; z++)
    s += b2f(Pb[(size_t)z * (NQ * 256) + (size_t)q * 256 + c]);
  s += bi1[c];
  s = fmaxf(s, 0.f);

  __shared__ float part[3][4];
  float p0 = s * Wi2[c], p1 = s * Wi2[256 + c], p2 = s * Wi2[512 + c];
  #pragma unroll
  for (int off = 32; off; off >>= 1) {
    p0 += __shfl_xor(p0, off);
    p1 += __shfl_xor(p1, off);
    p2 += __shfl_xor(p2, off);
  }
  if ((c & 63) == 0) {
    int w = c >> 6;
    part[0][w] = p0; part[1][w] = p1; part[2][w] = p2;
  }
  __syncthreads();
  if (c < 3)
    out[q * 3 + c] = bi2[c] + skipb[q * 3 + c]
                   + part[c][0] + part[c][1] + part[c][2] + part[c][3];
}

// ---------------------------------------------------------------------------
// softmax over 49 taps per head. block 512 (8 waves = 8 heads), grid NQ.
// ---------------------------------------------------------------------------
__global__ __launch_bounds__(512)
void softmax_k(const float* __restrict__ wc, float* __restrict__ attnval)
{
  const int q = blockIdx.x;
  const int tid = threadIdx.x;
  const int hh = tid >> 6, l = tid & 63;
  float v = (l < 49) ? wc[(size_t)q * 49 + l] + attnval[((size_t)q * 49 + l) * 8 + hh]
                     : -1e30f;
  float m = v;
  #pragma unroll
  for (int off = 32; off; off >>= 1) m = fmaxf(m, __shfl_xor(m, off));
  float e = (l < 49) ? expf(v - m) : 0.f;
  float s = e;
  #pragma unroll
  for (int off = 32; off; off >>= 1) s += __shfl_xor(s, off);
  if (l < 49) attnval[((size_t)q * 49 + l) * 8 + hh] = e / s;
}

// ---------------------------------------------------------------------------
// Weight packing — single launch for everything.
// ---------------------------------------------------------------------------
static __device__ __forceinline__
void packconv(const float* __restrict__ W, u16* __restrict__ Bt,
              int Cin, int K2, int idx)
{
  int o  = idx / (Cin * K2);
  int r  = idx - o * (Cin * K2);
  int ci = r / K2;
  int s  = r - ci * K2;
  Bt[(size_t)o * (Cin * K2) + s * Cin + ci] = f2b(W[idx]);
}
static __device__ __forceinline__
void packcast(const float* __restrict__ W, u16* __restrict__ Bt,
              int Kin, int Kout, int idx)
{
  int n = idx / Kout, k = idx - n * Kout;
  Bt[idx] = f2b(k < Kin ? W[(size_t)n * Kin + k] : 0.f);
}

#define SZ_CH   147456   // 256*64*9
#define SZ_QKV  589824   // 256*256*9
#define SZ_OFF1 204800   // 256*32*25
#define SZ_OFF2 25088    // 98*256
#define SZ_C1   32768    // 256*128
#define SZ_C2   12544    // 49*256
#define SZ_WI1  3219456  // 256*12576
#define SZ_PACK (SZ_CH + 3*SZ_QKV + SZ_OFF1 + SZ_OFF2 + SZ_C1 + SZ_C2 + 768 + SZ_WI1)

__global__ void pack_all(const float* W_ch, const float* W_q, const float* W_k,
                         const float* W_v, const float* W_off1, const float* W_off2,
                         const float* Wc1, const float* Wc2, const float* Wi1,
                         const float* b_q, const float* b_k, const float* b_v,
                         u16* Btch, u16* Btqkv, u16* Btoff1, u16* Btoff2,
                         u16* Btc1, u16* Btc2, u16* Wi1p, float* bqkv)
{
  int i = blockIdx.x * 256 + threadIdx.x;
  if (i < SZ_CH) { packconv(W_ch, Btch, 64, 9, i); return; }
  i -= SZ_CH;
  if (i < SZ_QKV) { packconv(W_q, Btqkv, 256, 9, i); return; }
  i -= SZ_QKV;
  if (i < SZ_QKV) { packconv(W_k, Btqkv + (size_t)256 * 2304, 256, 9, i); return; }
  i -= SZ_QKV;
  if (i < SZ_QKV) { packconv(W_v, Btqkv + (size_t)512 * 2304, 256, 9, i); return; }
  i -= SZ_QKV;
  if (i < SZ_OFF1) { packconv(W_off1, Btoff1, 32, 25, i); return; }
  i -= SZ_OFF1;
  if (i < SZ_OFF2) { packcast(W_off2, Btoff2, 256, 256, i); return; }
  i -= SZ_OFF2;
  if (i < SZ_C1) { packcast(Wc1, Btc1, 98, 128, i); return; }
  i -= SZ_C1;
  if (i < SZ_C2) { packcast(Wc2, Btc2, 256, 256, i); return; }
  i -= SZ_C2;
  if (i < 768) {
    bqkv[i] = (i < 256) ? b_q[i] : (i < 512) ? b_k[i - 256] : b_v[i - 512];
    return;
  }
  i -= 768;
  if (i < SZ_WI1) { packcast(Wi1, Wi1p, 12546, 12576, i); }
}

// ---------------------------------------------------------------------------
// Encoder conv: 3->64, 3x3 pad1, +bias, relu -> feat1 (HW,64) bf16
// ---------------------------------------------------------------------------
__global__ __launch_bounds__(64)
void conv_enc(const float* __restrict__ inp, const float* __restrict__ W,
              const float* __restrict__ b, u16* __restrict__ feat1)
{
  const int p = blockIdx.x, c = threadIdx.x;
  const int y = p >> 6, x = p & 63;
  float s = b[c];
  #pragma unroll
  for (int ci = 0; ci < 3; ci++)
    #pragma unroll
    for (int dy = 0; dy < 3; dy++) {
      int yy = y + dy - 1;
      if ((unsigned)yy >= 64u) continue;
      #pragma unroll
      for (int dx = 0; dx < 3; dx++) {
        int xx = x + dx - 1;
        if ((unsigned)xx >= 64u) continue;
        s += inp[ci * HW + yy * 64 + xx] * W[((c * 3 + ci) * 3 + dy) * 3 + dx];
      }
    }
  feat1[(size_t)p * 64 + c] = f2b(fmaxf(s, 0.f));
}

// ---------------------------------------------------------------------------
// LayerNorm(channel) + exact GELU
// ---------------------------------------------------------------------------
__global__ __launch_bounds__(256)
void ln_gelu(const float* __restrict__ x, const float* __restrict__ g,
             const float* __restrict__ b, u16* __restrict__ y)
{
  const int p = blockIdx.x, c = threadIdx.x;
  __shared__ float r1[4], r2[4];
  float v = x[(size_t)p * 256 + c];
  float s1 = v, s2 = v * v;
  #pragma unroll
  for (int off = 32; off; off >>= 1) {
    s1 += __shfl_xor(s1, off);
    s2 += __shfl_xor(s2, off);
  }
  if ((c & 63) == 0) { r1[c >> 6] = s1; r2[c >> 6] = s2; }
  __syncthreads();
  float t1 = r1[0] + r1[1] + r1[2] + r1[3];
  float t2 = r2[0] + r2[1] + r2[2] + r2[3];
  float mu  = t1 * (1.f / 256.f);
  float var = t2 * (1.f / 256.f) - mu * mu;
  float xn = (v - mu) * rsqrtf(var + 1e-5f) * g[c] + b[c];
  float ge = 0.5f * xn * (1.f + erff(xn * 0.70710678118654752f));
  y[(size_t)p * 256 + c] = f2b(ge);
}

// ---------------------------------------------------------------------------
// Per-query sampler (writes raw q.k dots to attnval; softmax_k finalizes).
// ---------------------------------------------------------------------------
__global__ __launch_bounds__(256)
void sampler(const float* __restrict__ coord, const u16* __restrict__ fqkvb,
             const float* __restrict__ offs, const float* __restrict__ inp,
             float* __restrict__ attnval, u16* __restrict__ relbuf,
             int* __restrict__ vidx, float* __restrict__ skipb)
{
  const int q = blockIdx.x;
  const int tid = threadIdx.x;
  __shared__ float s_off[98];
  __shared__ int s_idx[49];
  __shared__ float s_q[256];

  const float c0 = coord[q * 2], c1 = coord[q * 2 + 1];
  const float gxp = ((c1 + 1.f) * 64.f - 1.f) * 0.5f;
  const float gyp = ((c0 + 1.f) * 64.f - 1.f) * 0.5f;
  const int ixn = (int)rintf(gxp), iyn = (int)rintf(gyp);
  const bool inn = ((unsigned)ixn < 64u) && ((unsigned)iyn < 64u);

  if (tid < 98) {
    float v = inn ? offs[(size_t)(iyn * 64 + ixn) * 98 + tid] : 0.f;
    s_off[tid] = tanhf(v) * (2.f / 63.f);
  }
  __syncthreads();

  const float scky = inn ? (-1.f + (float)(2 * iyn + 1) * (1.f / 64.f)) : 0.f;
  const float sckx = inn ? (-1.f + (float)(2 * ixn + 1) * (1.f / 64.f)) : 0.f;

  if (tid < 49) {
    const int a = tid / 7, bb = tid - a * 7;
    float sy = scky + (float)(a - 3) * (2.f / 64.f) + s_off[2 * tid];
    float sx = sckx + (float)(bb - 3) * (2.f / 64.f) + s_off[2 * tid + 1];
    relbuf[(size_t)q * 128 + 2 * tid]     = f2b((c0 - sy) * 64.f);
    relbuf[(size_t)q * 128 + 2 * tid + 1] = f2b((c1 - sx) * 64.f);
    float gx2 = ((sx + 1.f) * 64.f - 1.f) * 0.5f;
    float gy2 = ((sy + 1.f) * 64.f - 1.f) * 0.5f;
    int ix2 = (int)rintf(gx2), iy2 = (int)rintf(gy2);
    int id = (((unsigned)ix2 < 64u) && ((unsigned)iy2 < 64u)) ? (iy2 * 64 + ix2) : -1;
    s_idx[tid] = id;
    vidx[q * 49 + tid] = id;
  } else if (tid >= 98 && tid < 128) {
    relbuf[(size_t)q * 128 + tid] = 0;
  }

  {
    const float x0f = floorf(gxp), y0f = floorf(gyp);
    const float wx = gxp - x0f, wy = gyp - y0f;
    const int x0 = (int)x0f, y0 = (int)y0f;
    float qc = 0.f;
    #pragma unroll
    for (int t = 0; t < 4; t++) {
      int xi = x0 + (t & 1), yi = y0 + (t >> 1);
      if (((unsigned)xi < 64u) && ((unsigned)yi < 64u)) {
        float w = ((t & 1) ? wx : 1.f - wx) * ((t >> 1) ? wy : 1.f - wy);
        qc += w * b2f(fqkvb[(size_t)(yi * 64 + xi) * 768 + tid]);
      }
    }
    s_q[tid] = qc * 0.17677669529663687f;
  }

  if (tid < 3) {
    float gx = fminf(fmaxf(gxp, 0.f), 63.f);
    float gy = fminf(fmaxf(gyp, 0.f), 63.f);
    float xf = floorf(gx), yf = floorf(gy);
    float wxs = gx - xf, wys = gy - yf;
    int xa = (int)xf, ya = (int)yf;
    int xb = min(xa + 1, 63), yb = min(ya + 1, 63);
    const float* ch = inp + tid * HW;
    float v = (1.f - wxs) * (1.f - wys) * ch[ya * 64 + xa]
            + wxs * (1.f - wys) * ch[ya * 64 + xb]
            + (1.f - wxs) * wys * ch[yb * 64 + xa]
            + wxs * wys * ch[yb * 64 + xb];
    skipb[q * 3 + tid] = v;
  }
  __syncthreads();

  const int wave = tid >> 6, lane = tid & 63;
  const int half = lane >> 5, sub = lane & 31;
  const int ch0 = sub * 8;
  const int h = sub >> 2;
  float qv[8];
  #pragma unroll
  for (int i = 0; i < 8; i++) qv[i] = s_q[ch0 + i];

  for (int it = 0; it < 7; it++) {
    int j = it * 8 + wave * 2 + half;
    if (j >= 49) break;
    int id = s_idx[j];
    float p = 0.f;
    if (id >= 0) {
      uint4 kv = *(const uint4*)&fqkvb[(size_t)id * 768 + 256 + ch0];
      u32 w0 = kv.x, w1 = kv.y, w2 = kv.z, w3 = kv.w;
      p = fmaf(qv[0], __uint_as_float(w0 << 16), p);
      p = fmaf(qv[1], __uint_as_float(w0 & 0xffff0000u), p);
      p = fmaf(qv[2], __uint_as_float(w1 << 16), p);
      p = fmaf(qv[3], __uint_as_float(w1 & 0xffff0000u), p);
      p = fmaf(qv[4], __uint_as_float(w2 << 16), p);
      p = fmaf(qv[5], __uint_as_float(w2 & 0xffff0000u), p);
      p = fmaf(qv[6], __uint_as_float(w3 << 16), p);
      p = fmaf(qv[7], __uint_as_float(w3 & 0xffff0000u), p);
    }
    p += __shfl_down(p, 2, 4);
    p += __shfl_down(p, 1, 4);
    if ((sub & 3) == 0) attnval[((size_t)q * 49 + j) * 8 + h] = p;
  }
}

// ===========================================================================
extern "C" void kernel_launch(void* const* d_in, const int* in_sizes, int n_in,
                              void* d_out, int out_size, void* d_ws, size_t ws_size,
                              hipStream_t stream)
{
  const float* inp    = (const float*)d_in[0];
  const float* coord  = (const float*)d_in[1];
  const float* cell   = (const float*)d_in[2];
  const float* W_enc  = (const float*)d_in[3];
  const float* b_enc  = (const float*)d_in[4];
  const float* W_ch   = (const float*)d_in[5];
  const float* b_ch   = (const float*)d_in[6];
  const float* W_q    = (const float*)d_in[7];
  const float* b_q    = (const float*)d_in[8];
  const float* W_k    = (const float*)d_in[9];
  const float* b_k    = (const float*)d_in[10];
  const float* W_v    = (const float*)d_in[11];
  const float* b_v    = (const float*)d_in[12];
  const float* W_off1 = (const float*)d_in[13];
  const float* b_off1 = (const float*)d_in[14];
  const float* ln_g   = (const float*)d_in[15];
  const float* ln_b   = (const float*)d_in[16];
  const float* W_off2 = (const float*)d_in[17];
  const float* Wc1    = (const float*)d_in[18];
  const float* bc1    = (const float*)d_in[19];
  const float* Wc2    = (const float*)d_in[20];
  const float* bc2    = (const float*)d_in[21];
  const float* Wi1    = (const float*)d_in[22];
  const float* bi1    = (const float*)d_in[23];
  const float* Wi2    = (const float*)d_in[24];
  const float* bi2    = (const float*)d_in[25];

  char* base = (char*)d_ws;
  size_t off = 0;
  auto alloc = [&](size_t bytes) -> char* {
    char* r = base + off;
    off = (off + bytes + 255) & ~(size_t)255;
    return r;
  };

  // --- scratch region (dead before gemm_big runs; Pb aliases it) ---
  float* obuf   = (float*)alloc((size_t)HW * 256 * 4);
  u16*   ocg    = (u16*)  alloc((size_t)HW * 256 * 2);
  float* offsb  = (float*)alloc((size_t)HW * 98 * 4);
  u16*   feat1  = (u16*)  alloc((size_t)HW * 64 * 2);
  u16*   feat   = (u16*)  alloc((size_t)HW * 256 * 2);
  u16*   hid1   = (u16*)  alloc((size_t)NQ * 256 * 2);
  float* wcb    = (float*)alloc((size_t)NQ * 49 * 4);
  u16*   relbuf = (u16*)  alloc((size_t)NQ * 128 * 2);
  u16*   Btqkv  = (u16*)  alloc((size_t)768 * 2304 * 2);
  u16*   Btch   = (u16*)  alloc((size_t)256 * 576 * 2);
  u16*   Btoff1 = (u16*)  alloc((size_t)256 * 800 * 2);
  u16*   Btoff2 = (u16*)  alloc((size_t)98 * 256 * 2);
  u16*   Btc1   = (u16*)  alloc((size_t)256 * 128 * 2);
  u16*   Btc2   = (u16*)  alloc((size_t)49 * 256 * 2);
  // gemm_big bf16 partials alias scratch: 16 x 2MB = 33.6MB at base+0.
  u16* Pb = (u16*)base;
  // qkv bf16 partials at [36MB, 54.9MB): past live scratch (~19MB),
  // disjoint from Pb's 33.6MB, dead before gemm_big.
  u16* Pqb = (u16*)(base + ((size_t)36 << 20));
  {
    size_t need = ((size_t)36 << 20) + (size_t)QSPLIT * NQ * 768 * 2;
    if (off < need) off = (need + 255) & ~(size_t)255;
  }
  // --- persistent buffers ---
  u16*   fqkvb   = (u16*)  alloc((size_t)HW * 768 * 2);
  float* fqkvV   = (float*)alloc((size_t)HW * 256 * 4);
  float* attnval = (float*)alloc((size_t)NQ * 49 * 8 * 4);
  int*   vidxb   = (int*)  alloc((size_t)NQ * 49 * 4);
  float* skipb   = (float*)alloc((size_t)NQ * 3 * 4);
  u16*   Wi1p    = (u16*)  alloc((size_t)256 * KBIG * 2);
  float* bqkv    = (float*)alloc(768 * 4);
  (void)ws_size; (void)in_sizes; (void)n_in; (void)out_size;

  // --- weight packing (single launch) ---
  pack_all<<<(SZ_PACK + 255) / 256, 256, 0, stream>>>(
      W_ch, W_q, W_k, W_v, W_off1, W_off2, Wc1, Wc2, Wi1, b_q, b_k, b_v,
      Btch, Btqkv, Btoff1, Btoff2, Btc1, Btc2, Wi1p, bqkv);

  // --- conv stack (implicit im2col) ---
  conv_enc<<<HW, 64, 0, stream>>>(inp, W_enc, b_enc, feat1);
  gemm_conv<3, 6, 1><<<dim3(64, 4, 1), 256, 0, stream>>>(
      feat1, Btch, feat, b_ch, 256, 576, 256, /*bf16*/2, 64, 0, 0, 0, 0);
  gemm_qkv<<<dim3(64, 6, QSPLIT), 256, 0, stream>>>(feat, Btqkv, Pqb);
  reduce_qkv<<<(NQ * 96 + 255) / 256, 256, 0, stream>>>(Pqb, bqkv, fqkvb, fqkvV);
  gemm_conv<5, 5, 2><<<dim3(64, 1, 8), 256, 0, stream>>>(
      feat, Btoff1, obuf, b_off1, 32, 800, 256, 0, 256, 32,
      (long)32 * 800, 32, 32);
  ln_gelu<<<HW, 256, 0, stream>>>(obuf, ln_g, ln_b, ocg);
  gemm_bt<<<dim3(64, 2, 1), 256, 0, stream>>>(ocg, Btoff2, offsb, nullptr,
      98, 256, 98, 0, 0, 0, 0, 0);

  // --- per-query attention path ---
  sampler<<<NQ, 256, 0, stream>>>(coord, fqkvb, offsb, inp,
                                  attnval, relbuf, vidxb, skipb);
  gemm_bt<<<dim3(64, 4, 1), 256, 0, stream>>>(relbuf, Btc1, hid1, bc1,
      256, 128, 256, /*relu+bf16*/3, 0, 0, 0, 0);
  gemm_bt<<<dim3(64, 1, 1), 256, 0, stream>>>(hid1, Btc2, wcb, bc2,
      49, 256, 49, 0, 0, 0, 0, 0);
  softmax_k<<<NQ, 512, 0, stream>>>(wcb, attnval);

  // --- big MLP: 128x256 tile, gather-A, glds-B, split-K(16), bf16 P ---
  gemm_big<<<dim3(32, SPLITK), 512, 0, stream>>>(
      Wi1p, fqkvV, attnval, vidxb, cell, Pb);
  reduce_final<<<NQ, 256, 0, stream>>>(Pb, bi1, Wi2, bi2, skipb, (float*)d_out);
}

// Round 14
// 287.781 us; speedup vs baseline: 1.1358x; 1.0094x over previous
//
#include <hip/hip_runtime.h>
#include <hip/hip_bf16.h>

// ============================================================================
// IDASR pipeline on gfx950 — round 14.
// Change vs round 13 (single structural variable):
//  * gemm_feat: qkv GEMM (1152 blocks) and grouped off1 conv (512 blocks)
//    merged into ONE launch (block-level branch). Both depend only on feat
//    and previously serialized; now off1 overlaps qkv's tail.
// ============================================================================

typedef unsigned short u16;
typedef unsigned int u32;
using frag_ab = __attribute__((ext_vector_type(8))) short;  // 8 x bf16
using frag_cd = __attribute__((ext_vector_type(4))) float;  // 4 x f32 acc

#define HW 4096
#define NQ 4096
#define KBIG 12576
#define SPLITK 16
#define KCHUNK 800
#define KQ 2304
#define QSPLIT 3
#define QCHUNK 768
#define NBLK_QKV (64 * 6 * QSPLIT)   // 1152
#define NBLK_OFF1 (64 * 8)           // 512

static __device__ __forceinline__ u16 f2b(float f) {
  union { __hip_bfloat16 h; u16 u; } c; c.h = __float2bfloat16(f); return c.u;
}
static __device__ __forceinline__ float b2f(u16 v) {
  return __uint_as_float((u32)v << 16);
}
static __device__ __forceinline__ u32 pk2(float a, float b) {
  union { __hip_bfloat162 h; u32 u; } c;
  c.h = __float22bfloat162_rn(float2{a, b});
  return c.u;
}
// async global->LDS, 16B per lane. LDS dest is wave-uniform base + lane*16.
static __device__ __forceinline__ void glds16(const u16* g, u16* l) {
  __builtin_amdgcn_global_load_lds(
      (const __attribute__((address_space(1))) u32*)(g),
      (__attribute__((address_space(3))) u32*)(l), 16, 0, 0);
}

#define BM 64
#define BN 64
#define BK 32
#define LDSS 40   // padded lds row stride for reg-staged tiles

// ---------------------------------------------------------------------------
// Generic bf16 GEMM (64x64 tile): off2, c1, c2 layers.
// ---------------------------------------------------------------------------
__global__ __launch_bounds__(256)
void gemm_bt(const u16* __restrict__ A, const u16* __restrict__ Bt,
             void* __restrict__ Cv, const float* __restrict__ bias,
             int N, int K, int ldc, int flags,   // 1=relu, 2=bf16 out
             long sA, long sB, long sC, int sBias)
{
  __shared__ u16 As[BM * LDSS];
  __shared__ u16 Bs[BN * LDSS];
  const int z = blockIdx.z;
  A  += (long)z * sA;
  Bt += (long)z * sB;
  const float* bz = bias ? bias + (long)z * sBias : nullptr;

  const int tid  = threadIdx.x;
  const int m0   = blockIdx.x * BM;
  const int n0   = blockIdx.y * BN;
  const int wave = tid >> 6, lane = tid & 63;
  const int mw = (wave & 1) * 32, nw = (wave >> 1) * 32;
  const int lr = lane & 15, lk = lane >> 4;
  const int srow = tid >> 2, scol = (tid & 3) * 8;

  frag_cd acc[2][2] = {};
  const u16* aptr = A + (size_t)(m0 + srow) * K + scol;
  const bool bok  = (n0 + srow) < N;
  const u16* bptr = Bt + (size_t)(n0 + srow) * K + scol;

  uint4 av = *(const uint4*)(aptr);
  uint4 bv = bok ? *(const uint4*)(bptr) : uint4{0u, 0u, 0u, 0u};

  for (int k0 = 0; k0 < K; k0 += BK) {
    *(uint4*)&As[srow * LDSS + scol] = av;
    *(uint4*)&Bs[srow * LDSS + scol] = bv;
    __syncthreads();
    if (k0 + BK < K) {
      av = *(const uint4*)(aptr + k0 + BK);
      bv = bok ? *(const uint4*)(bptr + k0 + BK) : uint4{0u, 0u, 0u, 0u};
    }
    frag_ab af0 = *(const frag_ab*)&As[(mw      + lr) * LDSS + lk * 8];
    frag_ab af1 = *(const frag_ab*)&As[(mw + 16 + lr) * LDSS + lk * 8];
    frag_ab bf0 = *(const frag_ab*)&Bs[(nw      + lr) * LDSS + lk * 8];
    frag_ab bf1 = *(const frag_ab*)&Bs[(nw + 16 + lr) * LDSS + lk * 8];
    acc[0][0] = __builtin_amdgcn_mfma_f32_16x16x32_bf16(af0, bf0, acc[0][0], 0, 0, 0);
    acc[0][1] = __builtin_amdgcn_mfma_f32_16x16x32_bf16(af0, bf1, acc[0][1], 0, 0, 0);
    acc[1][0] = __builtin_amdgcn_mfma_f32_16x16x32_bf16(af1, bf0, acc[1][0], 0, 0, 0);
    acc[1][1] = __builtin_amdgcn_mfma_f32_16x16x32_bf16(af1, bf1, acc[1][1], 0, 0, 0);
    __syncthreads();
  }

  const bool relu = flags & 1;
  const bool obf  = flags & 2;
  #pragma unroll
  for (int i = 0; i < 2; i++)
    #pragma unroll
    for (int j = 0; j < 2; j++) {
      int col = n0 + nw + j * 16 + lr;
      if (col >= N) continue;
      float badd = bz ? bz[col] : 0.f;
      #pragma unroll
      for (int r = 0; r < 4; r++) {
        int row = m0 + mw + i * 16 + lk * 4 + r;
        float v = acc[i][j][r] + badd;
        if (relu) v = fmaxf(v, 0.f);
        size_t idx = (size_t)z * sC + (size_t)row * ldc + col;
        if (obf) ((u16*)Cv)[idx] = f2b(v);
        else     ((float*)Cv)[idx] = v;
      }
    }
}

// ---------------------------------------------------------------------------
// Implicit-im2col conv GEMM, 64x64 tile (ch conv only now).
// ---------------------------------------------------------------------------
template<int W3, int SH, int PAD>
__global__ __launch_bounds__(256)
void gemm_conv(const u16* __restrict__ feat, const u16* __restrict__ Bt,
               void* __restrict__ Cv, const float* __restrict__ bias,
               int N, int K, int ldc, int flags, int FC, int cbStride,
               long sB, long sC, int sBias)
{
  __shared__ u16 As[BM * LDSS];
  __shared__ u16 Bs[BN * LDSS];
  const int z = blockIdx.z;
  Bt += (long)z * sB;
  const float* bz = bias ? bias + (long)z * sBias : nullptr;
  const int cb = z * cbStride;

  const int tid  = threadIdx.x;
  const int m0   = blockIdx.x * BM;
  const int n0   = blockIdx.y * BN;
  const int wave = tid >> 6, lane = tid & 63;
  const int mw = (wave & 1) * 32, nw = (wave >> 1) * 32;
  const int lr = lane & 15, lk = lane >> 4;
  const int srow = tid >> 2, scol = (tid & 3) * 8;
  const int p = m0 + srow, y = p >> 6, x = p & 63;

  frag_cd acc[2][2] = {};
  const bool bok  = (n0 + srow) < N;
  const u16* bptr = Bt + (size_t)(n0 + srow) * K + scol;

  auto stageA = [&](int k0) -> uint4 {
    int k = k0 + scol;
    int s = k >> SH;
    int c = k & ((1 << SH) - 1);
    int dy = s / W3, dx = s - dy * W3;
    int yy = y + dy - PAD, xx = x + dx - PAD;
    if (((unsigned)yy < 64u) && ((unsigned)xx < 64u))
      return *(const uint4*)&feat[(size_t)(yy * 64 + xx) * FC + cb + c];
    return uint4{0u, 0u, 0u, 0u};
  };

  uint4 av = stageA(0);
  uint4 bv = bok ? *(const uint4*)(bptr) : uint4{0u, 0u, 0u, 0u};

  for (int k0 = 0; k0 < K; k0 += BK) {
    *(uint4*)&As[srow * LDSS + scol] = av;
    *(uint4*)&Bs[srow * LDSS + scol] = bv;
    __syncthreads();
    if (k0 + BK < K) {
      av = stageA(k0 + BK);
      bv = bok ? *(const uint4*)(bptr + k0 + BK) : uint4{0u, 0u, 0u, 0u};
    }
    frag_ab af0 = *(const frag_ab*)&As[(mw      + lr) * LDSS + lk * 8];
    frag_ab af1 = *(const frag_ab*)&As[(mw + 16 + lr) * LDSS + lk * 8];
    frag_ab bf0 = *(const frag_ab*)&Bs[(nw      + lr) * LDSS + lk * 8];
    frag_ab bf1 = *(const frag_ab*)&Bs[(nw + 16 + lr) * LDSS + lk * 8];
    acc[0][0] = __builtin_amdgcn_mfma_f32_16x16x32_bf16(af0, bf0, acc[0][0], 0, 0, 0);
    acc[0][1] = __builtin_amdgcn_mfma_f32_16x16x32_bf16(af0, bf1, acc[0][1], 0, 0, 0);
    acc[1][0] = __builtin_amdgcn_mfma_f32_16x16x32_bf16(af1, bf0, acc[1][0], 0, 0, 0);
    acc[1][1] = __builtin_amdgcn_mfma_f32_16x16x32_bf16(af1, bf1, acc[1][1], 0, 0, 0);
    __syncthreads();
  }

  const bool relu = flags & 1;
  const bool obf  = flags & 2;
  #pragma unroll
  for (int i = 0; i < 2; i++)
    #pragma unroll
    for (int j = 0; j < 2; j++) {
      int col = n0 + nw + j * 16 + lr;
      if (col >= N) continue;
      float badd = bz ? bz[col] : 0.f;
      #pragma unroll
      for (int r = 0; r < 4; r++) {
        int row = m0 + mw + i * 16 + lk * 4 + r;
        float v = acc[i][j][r] + badd;
        if (relu) v = fmaxf(v, 0.f);
        size_t idx = (size_t)z * sC + (size_t)row * ldc + col;
        if (obf) ((u16*)Cv)[idx] = f2b(v);
        else     ((float*)Cv)[idx] = v;
      }
    }
}

// ---------------------------------------------------------------------------
// Merged feat-consumer kernel: blocks [0,1152) = qkv GEMM (64x128 tile,
// implicit im2col A, glds-B, split-K(3), bf16 partials); blocks
// [1152,1664) = grouped 5x5 off1 conv (64x64 tile). One launch -> overlap.
// ---------------------------------------------------------------------------
__global__ __launch_bounds__(256)
void gemm_feat(const u16* __restrict__ feat, const u16* __restrict__ Btqkv,
               u16* __restrict__ Pq, const u16* __restrict__ Btoff1,
               float* __restrict__ obuf, const float* __restrict__ b_off1)
{
  __shared__ u16 smem[6656];   // 13.3 KB: qkv As(2560)+Bs(4096); off1 uses 5120
  const int bid = blockIdx.x;
  const int tid = threadIdx.x;
  const int wave = tid >> 6, lane = tid & 63;
  const int lr = lane & 15, lk = lane >> 4;

  if (bid < NBLK_QKV) {
    // ----- qkv branch -----
    u16* As = smem;            // 64 * 40
    u16* Bs = smem + 64 * 40;  // 128 * 32, glds target
    const int mz  = bid & 63;
    const int rest = bid >> 6;
    const int ny  = rest % 6;
    const int z   = rest / 6;
    const int m0  = mz * 64;
    const int n0  = ny * 128;
    const int kbeg = z * QCHUNK;
    const int kend = kbeg + QCHUNK;
    const int nw = wave * 32;
    const int arow = tid >> 2, acol = (tid & 3) * 8;
    const int p = m0 + arow, y = p >> 6, x = p & 63;

    frag_cd acc[4][2] = {};
    const u16* bbase = Btqkv + (size_t)(n0 + (tid >> 2)) * KQ + (tid & 3) * 8 + kbeg;
    u16* bdst = &Bs[(size_t)tid * 8];

    auto stageA = [&](int k0) -> uint4 {
      int k = k0 + acol;
      int s = k >> 8, c = k & 255;
      int dy = s / 3, dx = s - dy * 3;
      int yy = y + dy - 1, xx = x + dx - 1;
      if (((unsigned)yy < 64u) && ((unsigned)xx < 64u))
        return *(const uint4*)&feat[(size_t)(yy * 64 + xx) * 256 + c];
      return uint4{0u, 0u, 0u, 0u};
    };

    uint4 av = stageA(kbeg);

    for (int k0 = kbeg; k0 < kend; k0 += BK) {
      glds16(bbase + (k0 - kbeg), bdst);
      glds16(bbase + (k0 - kbeg) + (size_t)64 * KQ, bdst + 2048);
      *(uint4*)&As[arow * LDSS + acol] = av;
      __syncthreads();
      if (k0 + BK < kend) av = stageA(k0 + BK);
      frag_ab af[4];
      #pragma unroll
      for (int i = 0; i < 4; i++)
        af[i] = *(const frag_ab*)&As[(i * 16 + lr) * LDSS + lk * 8];
      #pragma unroll
      for (int j = 0; j < 2; j++) {
        frag_ab bf = *(const frag_ab*)&Bs[(nw + j * 16 + lr) * 32 + lk * 8];
        #pragma unroll
        for (int i = 0; i < 4; i++)
          acc[i][j] = __builtin_amdgcn_mfma_f32_16x16x32_bf16(af[i], bf, acc[i][j], 0, 0, 0);
      }
      __syncthreads();
    }

    #pragma unroll
    for (int i = 0; i < 4; i++)
      #pragma unroll
      for (int j = 0; j < 2; j++) {
        int col = n0 + nw + j * 16 + lr;
        #pragma unroll
        for (int r = 0; r < 4; r++) {
          int row = m0 + i * 16 + lk * 4 + r;
          Pq[(size_t)z * (NQ * 768) + (size_t)row * 768 + col] = f2b(acc[i][j][r]);
        }
      }
  } else {
    // ----- off1 grouped conv branch (5x5 pad2, 32 ch/group) -----
    u16* As = smem;            // 64 * 40
    u16* Bs = smem + 64 * 40;  // 64 * 40
    const int t  = bid - NBLK_QKV;
    const int m0 = (t & 63) * 64;
    const int g  = t >> 6;               // group 0..7
    const int cb = g * 32;
    const u16* Bt = Btoff1 + (size_t)g * 32 * 800;
    const float* bz = b_off1 + g * 32;
    const int mw = (wave & 1) * 32, nw = (wave >> 1) * 32;
    const int srow = tid >> 2, scol = (tid & 3) * 8;
    const int p = m0 + srow, y = p >> 6, x = p & 63;

    frag_cd acc[2][2] = {};
    const bool bok  = srow < 32;
    const u16* bptr = Bt + (size_t)srow * 800 + scol;

    auto stageA = [&](int k0) -> uint4 {
      int k = k0 + scol;
      int s = k >> 5;
      int c = k & 31;
      int dy = s / 5, dx = s - dy * 5;
      int yy = y + dy - 2, xx = x + dx - 2;
      if (((unsigned)yy < 64u) && ((unsigned)xx < 64u))
        return *(const uint4*)&feat[(size_t)(yy * 64 + xx) * 256 + cb + c];
      return uint4{0u, 0u, 0u, 0u};
    };

    uint4 av = stageA(0);
    uint4 bv = bok ? *(const uint4*)(bptr) : uint4{0u, 0u, 0u, 0u};

    for (int k0 = 0; k0 < 800; k0 += BK) {
      *(uint4*)&As[srow * LDSS + scol] = av;
      *(uint4*)&Bs[srow * LDSS + scol] = bv;
      __syncthreads();
      if (k0 + BK < 800) {
        av = stageA(k0 + BK);
        bv = bok ? *(const uint4*)(bptr + k0 + BK) : uint4{0u, 0u, 0u, 0u};
      }
      frag_ab af0 = *(const frag_ab*)&As[(mw      + lr) * LDSS + lk * 8];
      frag_ab af1 = *(const frag_ab*)&As[(mw + 16 + lr) * LDSS + lk * 8];
      frag_ab bf0 = *(const frag_ab*)&Bs[(nw      + lr) * LDSS + lk * 8];
      frag_ab bf1 = *(const frag_ab*)&Bs[(nw + 16 + lr) * LDSS + lk * 8];
      acc[0][0] = __builtin_amdgcn_mfma_f32_16x16x32_bf16(af0, bf0, acc[0][0], 0, 0, 0);
      acc[0][1] = __builtin_amdgcn_mfma_f32_16x16x32_bf16(af0, bf1, acc[0][1], 0, 0, 0);
      acc[1][0] = __builtin_amdgcn_mfma_f32_16x16x32_bf16(af1, bf0, acc[1][0], 0, 0, 0);
      acc[1][1] = __builtin_amdgcn_mfma_f32_16x16x32_bf16(af1, bf1, acc[1][1], 0, 0, 0);
      __syncthreads();
    }

    #pragma unroll
    for (int i = 0; i < 2; i++)
      #pragma unroll
      for (int j = 0; j < 2; j++) {
        int col = nw + j * 16 + lr;
        if (col >= 32) continue;
        float badd = bz[col];
        #pragma unroll
        for (int r = 0; r < 4; r++) {
          int row = m0 + mw + i * 16 + lk * 4 + r;
          obuf[(size_t)row * 256 + g * 32 + col] = acc[i][j][r] + badd;
        }
      }
  }
}

// sum QSPLIT bf16 qkv partials + bias -> fqkvb (bf16) and fqkvV (f32 V).
__global__ __launch_bounds__(256)
void reduce_qkv(const u16* __restrict__ P, const float* __restrict__ bias,
                u16* __restrict__ outb, float* __restrict__ outV)
{
  int i8 = blockIdx.x * 256 + threadIdx.x;
  if (i8 >= NQ * 96) return;
  size_t i = (size_t)i8 * 8;
  int row = (int)(i / 768);
  int c = (int)(i % 768);
  float v[8];
  #pragma unroll
  for (int t = 0; t < 8; t++) v[t] = bias[c + t];
  for (int z = 0; z < QSPLIT; z++) {
    uint4 a = *(const uint4*)&P[(size_t)z * (NQ * 768) + i];
    u32 aw[4] = {a.x, a.y, a.z, a.w};
    #pragma unroll
    for (int t = 0; t < 4; t++) {
      v[2 * t]     += __uint_as_float(aw[t] << 16);
      v[2 * t + 1] += __uint_as_float(aw[t] & 0xffff0000u);
    }
  }
  uint4 ob = {pk2(v[0], v[1]), pk2(v[2], v[3]), pk2(v[4], v[5]), pk2(v[6], v[7])};
  *(uint4*)&outb[i] = ob;
  if (c >= 512) {
    float* dst = outV + (size_t)row * 256 + (c - 512);
    *(float4*)dst       = float4{v[0], v[1], v[2], v[3]};
    *(float4*)(dst + 4) = float4{v[4], v[5], v[6], v[7]};
  }
}

// ---------------------------------------------------------------------------
// Big MLP GEMM: fused gather-A (f32 V, deferred pack), 128x256 tile, glds-B,
// split-K(16), bf16 partials. block 512 (8 waves), grid (32, 16) = 2/CU.
// ---------------------------------------------------------------------------
__global__ __launch_bounds__(512, 4)
void gemm_big(const u16* __restrict__ Bt, const float* __restrict__ fqkvV,
              const float* __restrict__ attnval, const int* __restrict__ vidx,
              const float* __restrict__ cell, u16* __restrict__ P)
{
  __shared__ u16 As[128 * LDSS];         // 10 KB padded, reg-staged gather
  __shared__ u16 Bs[256 * 32];           // 16 KB unpadded, glds target
  __shared__ int   s_vidx[5 * 128];      // 2.5 KB
  __shared__ float s_attn[5 * 128 * 8];  // 20 KB
  const int tid  = threadIdx.x;
  const int m0   = blockIdx.x * 128;
  const int z    = blockIdx.y;
  const int kbeg = z * KCHUNK;
  const int kend = min(KBIG, kbeg + KCHUNK);
  const int jbeg = kbeg >> 8;
  const int jcnt = ((kend - 1) >> 8) - jbeg + 1;   // <= 5
  const int wave = tid >> 6, lane = tid & 63;
  const int mw = (wave & 1) * 64, nwv = (wave >> 1) * 64;
  const int lr = lane & 15, lk = lane >> 4;
  const int arow = tid >> 2, acol = (tid & 3) * 8;  // 128 rows x 4x8
  const int q = m0 + arow;

  for (int t = tid; t < 128 * jcnt; t += 512) {
    int r = t & 127, jj = t >> 7;
    int j = jbeg + jj;
    s_vidx[t] = (j < 49) ? vidx[(m0 + r) * 49 + j] : -1;
  }
  for (int t = tid; t < 128 * 8 * jcnt; t += 512) {
    int h = t & 7, rr = (t >> 3) & 127, jj = t >> 10;
    int j = jbeg + jj;
    s_attn[t] = (j < 49) ? attnval[((size_t)((m0 + rr) * 49 + j)) * 8 + h] : 0.f;
  }
  __syncthreads();

  auto loadA = [&](int k0, float4& f0, float4& f1, float& w) {
    const int k = k0 + acol;
    const int j = k >> 8, c = k & 255;
    f0 = float4{0.f, 0.f, 0.f, 0.f};
    f1 = float4{0.f, 0.f, 0.f, 0.f};
    w = 0.f;
    if (j < 49) {
      const int jj = j - jbeg;
      int id = s_vidx[jj * 128 + arow];
      if (id >= 0) {
        w = s_attn[(jj * 128 + arow) * 8 + (c >> 5)];
        const float* src = fqkvV + (size_t)id * 256 + c;
        f0 = *(const float4*)src;
        f1 = *(const float4*)(src + 4);
      }
    } else if (c == 0) {
      f0.x = cell[q * 2]; f0.y = cell[q * 2 + 1];
      w = 64.f;
    }
  };

  frag_cd acc[4][4] = {};
  float4 f0c, f1c; float wc_;
  loadA(kbeg, f0c, f1c, wc_);
  const u16* bbase = Bt + (size_t)(tid >> 2) * KBIG + (tid & 3) * 8 + kbeg;
  u16* bdst = &Bs[(size_t)tid * 8];

  for (int k0 = kbeg; k0 < kend; k0 += BK) {
    glds16(bbase + (k0 - kbeg), bdst);
    glds16(bbase + (k0 - kbeg) + (size_t)128 * KBIG, bdst + 4096);
    {
      uint4 av;
      av.x = pk2(f0c.x * wc_, f0c.y * wc_);
      av.y = pk2(f0c.z * wc_, f0c.w * wc_);
      av.z = pk2(f1c.x * wc_, f1c.y * wc_);
      av.w = pk2(f1c.z * wc_, f1c.w * wc_);
      *(uint4*)&As[arow * LDSS + acol] = av;
    }
    __syncthreads();
    if (k0 + BK < kend) loadA(k0 + BK, f0c, f1c, wc_);
    frag_ab af[4];
    #pragma unroll
    for (int i = 0; i < 4; i++)
      af[i] = *(const frag_ab*)&As[(mw + i * 16 + lr) * LDSS + lk * 8];
    #pragma unroll
    for (int j = 0; j < 4; j++) {
      frag_ab bf = *(const frag_ab*)&Bs[(nwv + j * 16 + lr) * 32 + lk * 8];
      #pragma unroll
      for (int i = 0; i < 4; i++)
        acc[i][j] = __builtin_amdgcn_mfma_f32_16x16x32_bf16(af[i], bf, acc[i][j], 0, 0, 0);
    }
    __syncthreads();
  }

  #pragma unroll
  for (int i = 0; i < 4; i++)
    #pragma unroll
    for (int j = 0; j < 4; j++) {
      int col = nwv + j * 16 + lr;
      #pragma unroll
      for (int r = 0; r < 4; r++) {
        int row = m0 + mw + i * 16 + lk * 4 + r;
        P[(size_t)z * (NQ * 256) + (size_t)row * 256 + col] = f2b(acc[i][j][r]);
      }
    }
}

// ---------------------------------------------------------------------------
// Fused: hid2 = relu(sum_z Pb + bi1); out = bi2 + skip + hid2 . Wi2^T.
// ---------------------------------------------------------------------------
__global__ __launch_bounds__(256)
void reduce_final(const u16* __restrict__ Pb, const float* __restrict__ bi1,
                  const float* __restrict__ Wi2, const float* __restrict__ bi2,
                  const float* __restrict__ skipb, float* __restrict__ out)
{
  const int q = blockIdx.x, c = threadIdx.x;
  float s = 0.f;
  #pragma unroll
  for (int z = 0; z < SPLITK; z++)
    s += b2f(Pb[(size_t)z * (NQ * 256) + (size_t)q * 256 + c]);
  s += bi1[c];
  s = fmaxf(s, 0.f);

  __shared__ float part[3][4];
  float p0 = s * Wi2[c], p1 = s * Wi2[256 + c], p2 = s * Wi2[512 + c];
  #pragma unroll
  for (int off = 32; off; off >>= 1) {
    p0 += __shfl_xor(p0, off);
    p1 += __shfl_xor(p1, off);
    p2 += __shfl_xor(p2, off);
  }
  if ((c & 63) == 0) {
    int w = c >> 6;
    part[0][w] = p0; part[1][w] = p1; part[2][w] = p2;
  }
  __syncthreads();
  if (c < 3)
    out[q * 3 + c] = bi2[c] + skipb[q * 3 + c]
                   + part[c][0] + part[c][1] + part[c][2] + part[c][3];
}

// ---------------------------------------------------------------------------
// softmax over 49 taps per head. block 512 (8 waves = 8 heads), grid NQ.
// ---------------------------------------------------------------------------
__global__ __launch_bounds__(512)
void softmax_k(const float* __restrict__ wc, float* __restrict__ attnval)
{
  const int q = blockIdx.x;
  const int tid = threadIdx.x;
  const int hh = tid >> 6, l = tid & 63;
  float v = (l < 49) ? wc[(size_t)q * 49 + l] + attnval[((size_t)q * 49 + l) * 8 + hh]
                     : -1e30f;
  float m = v;
  #pragma unroll
  for (int off = 32; off; off >>= 1) m = fmaxf(m, __shfl_xor(m, off));
  float e = (l < 49) ? expf(v - m) : 0.f;
  float s = e;
  #pragma unroll
  for (int off = 32; off; off >>= 1) s += __shfl_xor(s, off);
  if (l < 49) attnval[((size_t)q * 49 + l) * 8 + hh] = e / s;
}

// ---------------------------------------------------------------------------
// Weight packing — single launch for everything.
// ---------------------------------------------------------------------------
static __device__ __forceinline__
void packconv(const float* __restrict__ W, u16* __restrict__ Bt,
              int Cin, int K2, int idx)
{
  int o  = idx / (Cin * K2);
  int r  = idx - o * (Cin * K2);
  int ci = r / K2;
  int s  = r - ci * K2;
  Bt[(size_t)o * (Cin * K2) + s * Cin + ci] = f2b(W[idx]);
}
static __device__ __forceinline__
void packcast(const float* __restrict__ W, u16* __restrict__ Bt,
              int Kin, int Kout, int idx)
{
  int n = idx / Kout, k = idx - n * Kout;
  Bt[idx] = f2b(k < Kin ? W[(size_t)n * Kin + k] : 0.f);
}

#define SZ_CH   147456   // 256*64*9
#define SZ_QKV  589824   // 256*256*9
#define SZ_OFF1 204800   // 256*32*25
#define SZ_OFF2 25088    // 98*256
#define SZ_C1   32768    // 256*128
#define SZ_C2   12544    // 49*256
#define SZ_WI1  3219456  // 256*12576
#define SZ_PACK (SZ_CH + 3*SZ_QKV + SZ_OFF1 + SZ_OFF2 + SZ_C1 + SZ_C2 + 768 + SZ_WI1)

__global__ void pack_all(const float* W_ch, const float* W_q, const float* W_k,
                         const float* W_v, const float* W_off1, const float* W_off2,
                         const float* Wc1, const float* Wc2, const float* Wi1,
                         const float* b_q, const float* b_k, const float* b_v,
                         u16* Btch, u16* Btqkv, u16* Btoff1, u16* Btoff2,
                         u16* Btc1, u16* Btc2, u16* Wi1p, float* bqkv)
{
  int i = blockIdx.x * 256 + threadIdx.x;
  if (i < SZ_CH) { packconv(W_ch, Btch, 64, 9, i); return; }
  i -= SZ_CH;
  if (i < SZ_QKV) { packconv(W_q, Btqkv, 256, 9, i); return; }
  i -= SZ_QKV;
  if (i < SZ_QKV) { packconv(W_k, Btqkv + (size_t)256 * 2304, 256, 9, i); return; }
  i -= SZ_QKV;
  if (i < SZ_QKV) { packconv(W_v, Btqkv + (size_t)512 * 2304, 256, 9, i); return; }
  i -= SZ_QKV;
  if (i < SZ_OFF1) { packconv(W_off1, Btoff1, 32, 25, i); return; }
  i -= SZ_OFF1;
  if (i < SZ_OFF2) { packcast(W_off2, Btoff2, 256, 256, i); return; }
  i -= SZ_OFF2;
  if (i < SZ_C1) { packcast(Wc1, Btc1, 98, 128, i); return; }
  i -= SZ_C1;
  if (i < SZ_C2) { packcast(Wc2, Btc2, 256, 256, i); return; }
  i -= SZ_C2;
  if (i < 768) {
    bqkv[i] = (i < 256) ? b_q[i] : (i < 512) ? b_k[i - 256] : b_v[i - 512];
    return;
  }
  i -= 768;
  if (i < SZ_WI1) { packcast(Wi1, Wi1p, 12546, 12576, i); }
}

// ---------------------------------------------------------------------------
// Encoder conv: 3->64, 3x3 pad1, +bias, relu -> feat1 (HW,64) bf16
// ---------------------------------------------------------------------------
__global__ __launch_bounds__(64)
void conv_enc(const float* __restrict__ inp, const float* __restrict__ W,
              const float* __restrict__ b, u16* __restrict__ feat1)
{
  const int p = blockIdx.x, c = threadIdx.x;
  const int y = p >> 6, x = p & 63;
  float s = b[c];
  #pragma unroll
  for (int ci = 0; ci < 3; ci++)
    #pragma unroll
    for (int dy = 0; dy < 3; dy++) {
      int yy = y + dy - 1;
      if ((unsigned)yy >= 64u) continue;
      #pragma unroll
      for (int dx = 0; dx < 3; dx++) {
        int xx = x + dx - 1;
        if ((unsigned)xx >= 64u) continue;
        s += inp[ci * HW + yy * 64 + xx] * W[((c * 3 + ci) * 3 + dy) * 3 + dx];
      }
    }
  feat1[(size_t)p * 64 + c] = f2b(fmaxf(s, 0.f));
}

// ---------------------------------------------------------------------------
// LayerNorm(channel) + exact GELU
// ---------------------------------------------------------------------------
__global__ __launch_bounds__(256)
void ln_gelu(const float* __restrict__ x, const float* __restrict__ g,
             const float* __restrict__ b, u16* __restrict__ y)
{
  const int p = blockIdx.x, c = threadIdx.x;
  __shared__ float r1[4], r2[4];
  float v = x[(size_t)p * 256 + c];
  float s1 = v, s2 = v * v;
  #pragma unroll
  for (int off = 32; off; off >>= 1) {
    s1 += __shfl_xor(s1, off);
    s2 += __shfl_xor(s2, off);
  }
  if ((c & 63) == 0) { r1[c >> 6] = s1; r2[c >> 6] = s2; }
  __syncthreads();
  float t1 = r1[0] + r1[1] + r1[2] + r1[3];
  float t2 = r2[0] + r2[1] + r2[2] + r2[3];
  float mu  = t1 * (1.f / 256.f);
  float var = t2 * (1.f / 256.f) - mu * mu;
  float xn = (v - mu) * rsqrtf(var + 1e-5f) * g[c] + b[c];
  float ge = 0.5f * xn * (1.f + erff(xn * 0.70710678118654752f));
  y[(size_t)p * 256 + c] = f2b(ge);
}

// ---------------------------------------------------------------------------
// Per-query sampler (writes raw q.k dots to attnval; softmax_k finalizes).
// ---------------------------------------------------------------------------
__global__ __launch_bounds__(256)
void sampler(const float* __restrict__ coord, const u16* __restrict__ fqkvb,
             const float* __restrict__ offs, const float* __restrict__ inp,
             float* __restrict__ attnval, u16* __restrict__ relbuf,
             int* __restrict__ vidx, float* __restrict__ skipb)
{
  const int q = blockIdx.x;
  const int tid = threadIdx.x;
  __shared__ float s_off[98];
  __shared__ int s_idx[49];
  __shared__ float s_q[256];

  const float c0 = coord[q * 2], c1 = coord[q * 2 + 1];
  const float gxp = ((c1 + 1.f) * 64.f - 1.f) * 0.5f;
  const float gyp = ((c0 + 1.f) * 64.f - 1.f) * 0.5f;
  const int ixn = (int)rintf(gxp), iyn = (int)rintf(gyp);
  const bool inn = ((unsigned)ixn < 64u) && ((unsigned)iyn < 64u);

  if (tid < 98) {
    float v = inn ? offs[(size_t)(iyn * 64 + ixn) * 98 + tid] : 0.f;
    s_off[tid] = tanhf(v) * (2.f / 63.f);
  }
  __syncthreads();

  const float scky = inn ? (-1.f + (float)(2 * iyn + 1) * (1.f / 64.f)) : 0.f;
  const float sckx = inn ? (-1.f + (float)(2 * ixn + 1) * (1.f / 64.f)) : 0.f;

  if (tid < 49) {
    const int a = tid / 7, bb = tid - a * 7;
    float sy = scky + (float)(a - 3) * (2.f / 64.f) + s_off[2 * tid];
    float sx = sckx + (float)(bb - 3) * (2.f / 64.f) + s_off[2 * tid + 1];
    relbuf[(size_t)q * 128 + 2 * tid]     = f2b((c0 - sy) * 64.f);
    relbuf[(size_t)q * 128 + 2 * tid + 1] = f2b((c1 - sx) * 64.f);
    float gx2 = ((sx + 1.f) * 64.f - 1.f) * 0.5f;
    float gy2 = ((sy + 1.f) * 64.f - 1.f) * 0.5f;
    int ix2 = (int)rintf(gx2), iy2 = (int)rintf(gy2);
    int id = (((unsigned)ix2 < 64u) && ((unsigned)iy2 < 64u)) ? (iy2 * 64 + ix2) : -1;
    s_idx[tid] = id;
    vidx[q * 49 + tid] = id;
  } else if (tid >= 98 && tid < 128) {
    relbuf[(size_t)q * 128 + tid] = 0;
  }

  {
    const float x0f = floorf(gxp), y0f = floorf(gyp);
    const float wx = gxp - x0f, wy = gyp - y0f;
    const int x0 = (int)x0f, y0 = (int)y0f;
    float qc = 0.f;
    #pragma unroll
    for (int t = 0; t < 4; t++) {
      int xi = x0 + (t & 1), yi = y0 + (t >> 1);
      if (((unsigned)xi < 64u) && ((unsigned)yi < 64u)) {
        float w = ((t & 1) ? wx : 1.f - wx) * ((t >> 1) ? wy : 1.f - wy);
        qc += w * b2f(fqkvb[(size_t)(yi * 64 + xi) * 768 + tid]);
      }
    }
    s_q[tid] = qc * 0.17677669529663687f;
  }

  if (tid < 3) {
    float gx = fminf(fmaxf(gxp, 0.f), 63.f);
    float gy = fminf(fmaxf(gyp, 0.f), 63.f);
    float xf = floorf(gx), yf = floorf(gy);
    float wxs = gx - xf, wys = gy - yf;
    int xa = (int)xf, ya = (int)yf;
    int xb = min(xa + 1, 63), yb = min(ya + 1, 63);
    const float* ch = inp + tid * HW;
    float v = (1.f - wxs) * (1.f - wys) * ch[ya * 64 + xa]
            + wxs * (1.f - wys) * ch[ya * 64 + xb]
            + (1.f - wxs) * wys * ch[yb * 64 + xa]
            + wxs * wys * ch[yb * 64 + xb];
    skipb[q * 3 + tid] = v;
  }
  __syncthreads();

  const int wave = tid >> 6, lane = tid & 63;
  const int half = lane >> 5, sub = lane & 31;
  const int ch0 = sub * 8;
  const int h = sub >> 2;
  float qv[8];
  #pragma unroll
  for (int i = 0; i < 8; i++) qv[i] = s_q[ch0 + i];

  for (int it = 0; it < 7; it++) {
    int j = it * 8 + wave * 2 + half;
    if (j >= 49) break;
    int id = s_idx[j];
    float p = 0.f;
    if (id >= 0) {
      uint4 kv = *(const uint4*)&fqkvb[(size_t)id * 768 + 256 + ch0];
      u32 w0 = kv.x, w1 = kv.y, w2 = kv.z, w3 = kv.w;
      p = fmaf(qv[0], __uint_as_float(w0 << 16), p);
      p = fmaf(qv[1], __uint_as_float(w0 & 0xffff0000u), p);
      p = fmaf(qv[2], __uint_as_float(w1 << 16), p);
      p = fmaf(qv[3], __uint_as_float(w1 & 0xffff0000u), p);
      p = fmaf(qv[4], __uint_as_float(w2 << 16), p);
      p = fmaf(qv[5], __uint_as_float(w2 & 0xffff0000u), p);
      p = fmaf(qv[6], __uint_as_float(w3 << 16), p);
      p = fmaf(qv[7], __uint_as_float(w3 & 0xffff0000u), p);
    }
    p += __shfl_down(p, 2, 4);
    p += __shfl_down(p, 1, 4);
    if ((sub & 3) == 0) attnval[((size_t)q * 49 + j) * 8 + h] = p;
  }
}

// ===========================================================================
extern "C" void kernel_launch(void* const* d_in, const int* in_sizes, int n_in,
                              void* d_out, int out_size, void* d_ws, size_t ws_size,
                              hipStream_t stream)
{
  const float* inp    = (const float*)d_in[0];
  const float* coord  = (const float*)d_in[1];
  const float* cell   = (const float*)d_in[2];
  const float* W_enc  = (const float*)d_in[3];
  const float* b_enc  = (const float*)d_in[4];
  const float* W_ch   = (const float*)d_in[5];
  const float* b_ch   = (const float*)d_in[6];
  const float* W_q    = (const float*)d_in[7];
  const float* b_q    = (const float*)d_in[8];
  const float* W_k    = (const float*)d_in[9];
  const float* b_k    = (const float*)d_in[10];
  const float* W_v    = (const float*)d_in[11];
  const float* b_v    = (const float*)d_in[12];
  const float* W_off1 = (const float*)d_in[13];
  const float* b_off1 = (const float*)d_in[14];
  const float* ln_g   = (const float*)d_in[15];
  const float* ln_b   = (const float*)d_in[16];
  const float* W_off2 = (const float*)d_in[17];
  const float* Wc1    = (const float*)d_in[18];
  const float* bc1    = (const float*)d_in[19];
  const float* Wc2    = (const float*)d_in[20];
  const float* bc2    = (const float*)d_in[21];
  const float* Wi1    = (const float*)d_in[22];
  const float* bi1    = (const float*)d_in[23];
  const float* Wi2    = (const float*)d_in[24];
  const float* bi2    = (const float*)d_in[25];

  char* base = (char*)d_ws;
  size_t off = 0;
  auto alloc = [&](size_t bytes) -> char* {
    char* r = base + off;
    off = (off + bytes + 255) & ~(size_t)255;
    return r;
  };

  // --- scratch region (dead before gemm_big runs; Pb aliases it) ---
  float* obuf   = (float*)alloc((size_t)HW * 256 * 4);
  u16*   ocg    = (u16*)  alloc((size_t)HW * 256 * 2);
  float* offsb  = (float*)alloc((size_t)HW * 98 * 4);
  u16*   feat1  = (u16*)  alloc((size_t)HW * 64 * 2);
  u16*   feat   = (u16*)  alloc((size_t)HW * 256 * 2);
  u16*   hid1   = (u16*)  alloc((size_t)NQ * 256 * 2);
  float* wcb    = (float*)alloc((size_t)NQ * 49 * 4);
  u16*   relbuf = (u16*)  alloc((size_t)NQ * 128 * 2);
  u16*   Btqkv  = (u16*)  alloc((size_t)768 * 2304 * 2);
  u16*   Btch   = (u16*)  alloc((size_t)256 * 576 * 2);
  u16*   Btoff1 = (u16*)  alloc((size_t)256 * 800 * 2);
  u16*   Btoff2 = (u16*)  alloc((size_t)98 * 256 * 2);
  u16*   Btc1   = (u16*)  alloc((size_t)256 * 128 * 2);
  u16*   Btc2   = (u16*)  alloc((size_t)49 * 256 * 2);
  // gemm_big bf16 partials alias scratch: 16 x 2MB = 33.6MB at base+0.
  u16* Pb = (u16*)base;
  // qkv bf16 partials at [36MB, 54.9MB): past live scratch (~19MB),
  // disjoint from Pb's 33.6MB, dead before gemm_big.
  u16* Pqb = (u16*)(base + ((size_t)36 << 20));
  {
    size_t need = ((size_t)36 << 20) + (size_t)QSPLIT * NQ * 768 * 2;
    if (off < need) off = (need + 255) & ~(size_t)255;
  }
  // --- persistent buffers ---
  u16*   fqkvb   = (u16*)  alloc((size_t)HW * 768 * 2);
  float* fqkvV   = (float*)alloc((size_t)HW * 256 * 4);
  float* attnval = (float*)alloc((size_t)NQ * 49 * 8 * 4);
  int*   vidxb   = (int*)  alloc((size_t)NQ * 49 * 4);
  float* skipb   = (float*)alloc((size_t)NQ * 3 * 4);
  u16*   Wi1p    = (u16*)  alloc((size_t)256 * KBIG * 2);
  float* bqkv    = (float*)alloc(768 * 4);
  (void)ws_size; (void)in_sizes; (void)n_in; (void)out_size;

  // --- weight packing (single launch) ---
  pack_all<<<(SZ_PACK + 255) / 256, 256, 0, stream>>>(
      W_ch, W_q, W_k, W_v, W_off1, W_off2, Wc1, Wc2, Wi1, b_q, b_k, b_v,
      Btch, Btqkv, Btoff1, Btoff2, Btc1, Btc2, Wi1p, bqkv);

  // --- conv stack ---
  conv_enc<<<HW, 64, 0, stream>>>(inp, W_enc, b_enc, feat1);
  gemm_conv<3, 6, 1><<<dim3(64, 4, 1), 256, 0, stream>>>(
      feat1, Btch, feat, b_ch, 256, 576, 256, /*bf16*/2, 64, 0, 0, 0, 0);
  // merged qkv + off1 (overlap)
  gemm_feat<<<NBLK_QKV + NBLK_OFF1, 256, 0, stream>>>(
      feat, Btqkv, Pqb, Btoff1, obuf, b_off1);
  reduce_qkv<<<(NQ * 96 + 255) / 256, 256, 0, stream>>>(Pqb, bqkv, fqkvb, fqkvV);
  ln_gelu<<<HW, 256, 0, stream>>>(obuf, ln_g, ln_b, ocg);
  gemm_bt<<<dim3(64, 2, 1), 256, 0, stream>>>(ocg, Btoff2, offsb, nullptr,
      98, 256, 98, 0, 0, 0, 0, 0);

  // --- per-query attention path ---
  sampler<<<NQ, 256, 0, stream>>>(coord, fqkvb, offsb, inp,
                                  attnval, relbuf, vidxb, skipb);
  gemm_bt<<<dim3(64, 4, 1), 256, 0, stream>>>(relbuf, Btc1, hid1, bc1,
      256, 128, 256, /*relu+bf16*/3, 0, 0, 0, 0);
  gemm_bt<<<dim3(64, 1, 1), 256, 0, stream>>>(hid1, Btc2, wcb, bc2,
      49, 256, 49, 0, 0, 0, 0, 0);
  softmax_k<<<NQ, 512, 0, stream>>>(wcb, attnval);

  // --- big MLP: 128x256 tile, gather-A, glds-B, split-K(16), bf16 P ---
  gemm_big<<<dim3(32, SPLITK), 512, 0, stream>>>(
      Wi1p, fqkvV, attnval, vidxb, cell, Pb);
  reduce_final<<<NQ, 256, 0, stream>>>(Pb, bi1, Wi2, bi2, skipb, (float*)d_out);
}